// Round 10
// baseline (592.134 us; speedup 1.0000x reference)
//
#include <hip/hip_runtime.h>
#include <hip/hip_bf16.h>
#include <hip/hip_cooperative_groups.h>

#define NBANDS 5
#define BATCH  16
#define DIM    256
#define NNODE  64
#define SEQ    5
#define NHEAD  4
#define DHEAD  64

namespace cg = cooperative_groups;

typedef __hip_bfloat16 bf16;
typedef unsigned short ushort_t;
typedef __attribute__((ext_vector_type(8))) short short8;   // 8 bf16 (4 VGPRs)
typedef __attribute__((ext_vector_type(4))) float float4v;  // 4 fp32 acc

__device__ __forceinline__ float bu2f(ushort_t u){
    bf16 h = *reinterpret_cast<bf16*>(&u);
    return __bfloat162float(h);
}
__device__ __forceinline__ ushort_t f2bu(float x){
    bf16 h = __float2bfloat16(x);
    return *reinterpret_cast<ushort_t*>(&h);
}

struct P {
    const float *l_adj_w, *l_pos_enc, *l_pf, *g_adj_w, *g_pos_enc, *g_pf;
    const float *w1, *gw, *feat, *b1, *w2, *b2arr, *gb;
    const float *imp_w, *imp_b;
    const float *qkv_w, *qkv_b, *attn_ow, *attn_ob;
    const float *ln1_g, *ln1_b, *mlp_w1, *mlp_b1, *mlp_w2, *mlp_b2, *ln2_g, *ln2_b;
    const float *g_sim_w1, *g_sim_b1, *g_sim_w2, *g_sim_b2, *g_gcn_w, *g_gcn_b;
    float *sbase, *gbase;
    ushort_t *w1bt, *gwbt, *xtb, *xtT, *aab, *bbb, *yb, *combb;
    float *scalew, *impw, *qkvw, *projw, *h1w, *mhw, *m2w, *sew, *gaw, *gbw;
    float *out0, *out_gadj, *out_local;
};

__device__ __forceinline__ float block_ln(float v, int tid, float* red, float g, float bln)
{
    float s = v;
    for (int o=32;o>0;o>>=1) s += __shfl_xor(s,o,64);
    int wave = tid>>6, lane = tid&63;
    if (lane==0) red[wave] = s;
    __syncthreads();
    float mean = (red[0]+red[1]+red[2]+red[3]) * (1.f/DIM);
    float c = v - mean;
    float q = c*c;
    for (int o=32;o>0;o>>=1) q += __shfl_xor(q,o,64);
    __syncthreads();
    if (lane==0) red[wave] = q;
    __syncthreads();
    float var = (red[0]+red[1]+red[2]+red[3]) * (1.f/DIM);
    return c * rsqrtf(var + 1e-5f) * g + bln;
}

// ======================= stage device bodies (shared by mega & fallback) ====

__device__ __forceinline__ void st_head_unit(const P& p, int blk, int tid, char* smem)
{
    ushort_t (*tile)[65] = (ushort_t(*)[65])smem;
    if (blk < 80) {
        int r = blk*4 + (tid>>6);
        int k = r >> 6, i = r & 63;
        int t = tid & 63;
        float aw = p.l_adj_w[(k*NNODE + i)*NNODE + t];
        float pe = p.l_pos_enc[(k*NNODE + i)*NNODE + t];
        float m1 = aw, m2 = pe;
        for (int o=32;o>0;o>>=1){ m1 = fmaxf(m1, __shfl_xor(m1,o,64)); m2 = fmaxf(m2, __shfl_xor(m2,o,64)); }
        float e1 = __expf(aw-m1), e2 = __expf(pe-m2);
        float s1=e1, s2=e2;
        for (int o=32;o>0;o>>=1){ s1 += __shfl_xor(s1,o,64); s2 += __shfl_xor(s2,o,64); }
        float pf = p.l_pf[k];
        p.sbase[(k*NNODE+i)*NNODE + t] = e1/s1 + pf*(e2/s2);
    } else if (blk == 80) {
        if (tid < NBANDS) {
            int i = tid;
            float r1[NBANDS], r2[NBANDS];
            float m1=-1e30f, m2=-1e30f;
            for (int j=0;j<NBANDS;j++){
                r1[j]=p.g_adj_w[i*NBANDS+j]; r2[j]=p.g_pos_enc[i*NBANDS+j];
                m1=fmaxf(m1,r1[j]); m2=fmaxf(m2,r2[j]);
            }
            float s1=0.f,s2=0.f;
            for (int j=0;j<NBANDS;j++){ r1[j]=__expf(r1[j]-m1); r2[j]=__expf(r2[j]-m2); s1+=r1[j]; s2+=r2[j]; }
            float pf = p.g_pf[0];
            for (int j=0;j<NBANDS;j++) p.gbase[i*NBANDS+j] = r1[j]/s1 + pf*(r2[j]/s2);
        }
    } else if (blk < 321) {
        int idx = blk - 81;
        int inst = idx >> 4;
        int t = idx & 15;
        int r0 = (t>>2)*64, c0 = (t&3)*64;
        const float* src; ushort_t* dst;
        if (inst < 10){
            int k = inst>>1, half = inst&1;
            src = p.w1  + ((size_t)k*512 + half*256)*256;
            dst = p.w1bt+ ((size_t)k*512 + half*256)*256;
        } else {
            int k = inst-10;
            src = p.gw  + (size_t)k*65536;
            dst = p.gwbt+ (size_t)k*65536;
        }
        int jj = tid & 63, i4 = tid >> 6;
        for (int q=0;q<16;q++){
            int i = q*4 + i4;
            tile[i][jj] = f2bu(src[(size_t)(r0+i)*256 + c0 + jj]);
        }
        __syncthreads();
        for (int q=0;q<16;q++){
            int i = q*4 + i4;
            dst[(size_t)(c0+i)*256 + r0 + jj] = tile[jj][i];
        }
    } else {
        int idx = blk - 321;                   // (k,b,dt)
        int k = idx >> 6;
        int b = (idx >> 2) & 15;
        int dt = idx & 3;
        const float* src = p.feat + ((size_t)b*NBANDS*DIM + (size_t)k*DIM)*NNODE;
        ushort_t* dst = p.xtb + (size_t)(k*BATCH+b)*NNODE*DIM;
        ushort_t* dstT = p.xtT + (size_t)(k*BATCH+b)*DIM*NNODE;
        for (int u=0; u<16; ++u){
            int i = dt*4096 + u*256 + tid;
            dstT[i] = f2bu(src[i]);
        }
        for (int r=0;r<16;r++){
            int dp = r*4 + (tid>>6);
            int n  = tid & 63;
            tile[dp][n] = f2bu(src[(size_t)(dt*64+dp)*NNODE + n]);
        }
        __syncthreads();
        for (int r=0;r<16;r++){
            int n  = r*4 + (tid>>6);
            int dp = tid & 63;
            dst[(size_t)n*DIM + dt*64 + dp] = tile[dp][n];
        }
    }
}

__device__ __forceinline__ void st_ab_unit(const P& p, int blk, int tid)
{
    int wave = tid>>6, lane = tid&63;
    int c16 = lane & 15, quad = lane >> 4;
    int m0 = wave*16;
    int kband = blk / (BATCH*8);
    int b = (blk/8) % BATCH;
    int nblk = blk & 7;
    size_t rowbase = (size_t)(kband*BATCH+b)*NNODE;
    const ushort_t* Aptr = p.xtb + (rowbase + m0 + c16)*DIM + quad*8;
    const ushort_t* Bbase = p.w1bt + (size_t)kband*512*DIM;
    int ncol0 = nblk*64;
    const ushort_t* Bptr0 = Bbase + (size_t)(ncol0 +  0 + c16)*DIM + quad*8;
    const ushort_t* Bptr1 = Bbase + (size_t)(ncol0 + 16 + c16)*DIM + quad*8;
    const ushort_t* Bptr2 = Bbase + (size_t)(ncol0 + 32 + c16)*DIM + quad*8;
    const ushort_t* Bptr3 = Bbase + (size_t)(ncol0 + 48 + c16)*DIM + quad*8;
    float4v acc0 = {0.f,0.f,0.f,0.f}, acc1 = acc0, acc2 = acc0, acc3 = acc0;
    #pragma unroll
    for (int ks=0; ks<8; ++ks){
        short8 a  = *reinterpret_cast<const short8*>(Aptr  + ks*32);
        short8 b0 = *reinterpret_cast<const short8*>(Bptr0 + ks*32);
        short8 b1v= *reinterpret_cast<const short8*>(Bptr1 + ks*32);
        short8 b2 = *reinterpret_cast<const short8*>(Bptr2 + ks*32);
        short8 b3 = *reinterpret_cast<const short8*>(Bptr3 + ks*32);
        acc0 = __builtin_amdgcn_mfma_f32_16x16x32_bf16(a, b0, acc0, 0,0,0);
        acc1 = __builtin_amdgcn_mfma_f32_16x16x32_bf16(a, b1v, acc1, 0,0,0);
        acc2 = __builtin_amdgcn_mfma_f32_16x16x32_bf16(a, b2, acc2, 0,0,0);
        acc3 = __builtin_amdgcn_mfma_f32_16x16x32_bf16(a, b3, acc3, 0,0,0);
    }
    int half = nblk >> 2;
    int cbase = (nblk & 3)*64;
    ushort_t* dst = half ? p.bbb : p.aab;
    float4v accs[4] = {acc0, acc1, acc2, acc3};
    #pragma unroll
    for (int nt=0; nt<4; ++nt){
        int cg2 = cbase + nt*16 + c16;
        float bias = half ? 0.f : p.b1[kband*DIM + cg2];
        #pragma unroll
        for (int r=0;r<4;r++){
            int m = m0 + quad*4 + r;
            dst[(rowbase + m)*DIM + cg2] = f2bu(accs[nt][r] + bias);
        }
    }
}

__device__ __forceinline__ void st_dyn_unit(const P& p, int blk, int tid, char* smem)
{
    ushort_t (*bs)[260] = (ushort_t(*)[260])smem;
    float (*arows)[DIM] = (float(*)[DIM])(smem + 33280);
    float* w2s = (float*)(smem + 33280 + 4096);
    int wave = tid >> 6, lane = tid & 63;
    int k = blk / (BATCH*16);
    int b = (blk / 16) % BATCH;
    int i0 = (blk % 16) * 4;
    int kb = k*BATCH + b;
    const ushort_t* bsrc = p.bbb + (size_t)kb*NNODE*DIM;
    for (int u=0; u<16; ++u){
        int idx = u*1024 + tid*4;
        int row = idx >> 8, col = idx & 255;
        *reinterpret_cast<ushort4*>(&bs[row][col]) =
            *reinterpret_cast<const ushort4*>(&bsrc[(size_t)row*DIM + col]);
    }
    for (int r=0;r<4;r++) arows[r][tid] = bu2f(p.aab[((size_t)kb*NNODE + i0 + r)*DIM + tid]);
    w2s[tid] = p.w2[k*DIM + tid];
    __syncthreads();

    int i = i0 + wave;
    float acc = 0.f;
    #pragma unroll 4
    for (int dd=0; dd<64; ++dd){
        ushort4 bv = *reinterpret_cast<const ushort4*>(&bs[lane][dd*4]);
        float4 av = *reinterpret_cast<const float4*>(&arows[wave][dd*4]);
        float4 wv = *reinterpret_cast<const float4*>(&w2s[dd*4]);
        float v0 = av.x + bu2f(bv.x);
        float v1 = av.y + bu2f(bv.y);
        float v2 = av.z + bu2f(bv.z);
        float v3 = av.w + bu2f(bv.w);
        float e0 = (v0>0.f)? v0 : (__expf(v0)-1.f);
        float e1 = (v1>0.f)? v1 : (__expf(v1)-1.f);
        float e2 = (v2>0.f)? v2 : (__expf(v2)-1.f);
        float e3 = (v3>0.f)? v3 : (__expf(v3)-1.f);
        acc += e0*wv.x + e1*wv.y + e2*wv.z + e3*wv.w;
    }
    float sb2 = p.b2arr[k];
    float sg = 1.f/(1.f + __expf(-(acc + sb2)));
    float val = p.sbase[(k*NNODE + i)*NNODE + lane] + sg;
    float m = val;
    for (int o=32;o>0;o>>=1) m = fmaxf(m, __shfl_xor(m,o,64));
    float e = __expf(val - m);
    float s = e;
    for (int o=32;o>0;o>>=1) s += __shfl_xor(s,o,64);
    p.combb[((size_t)kb*NNODE + i)*NNODE + lane] = f2bu(e/s);
}

__device__ __forceinline__ void st_y_unit(const P& p, int blk, int tid)
{
    int wave = tid>>6, lane = tid&63;
    int c16 = lane & 15, quad = lane >> 4;
    int m0 = wave*16;
    int kband = blk / (BATCH*4);
    int b = (blk/4) % BATCH;
    int nblk = blk & 3;
    int kb = kband*BATCH + b;
    const ushort_t* Aptr = p.combb + ((size_t)kb*NNODE + m0 + c16)*NNODE + quad*8;
    const ushort_t* Bbase = p.xtT + (size_t)kb*DIM*NNODE;
    int ncol0 = nblk*64;
    const ushort_t* Bptr0 = Bbase + (size_t)(ncol0 +  0 + c16)*NNODE + quad*8;
    const ushort_t* Bptr1 = Bbase + (size_t)(ncol0 + 16 + c16)*NNODE + quad*8;
    const ushort_t* Bptr2 = Bbase + (size_t)(ncol0 + 32 + c16)*NNODE + quad*8;
    const ushort_t* Bptr3 = Bbase + (size_t)(ncol0 + 48 + c16)*NNODE + quad*8;
    float4v acc0 = {0.f,0.f,0.f,0.f}, acc1 = acc0, acc2 = acc0, acc3 = acc0;
    #pragma unroll
    for (int ks=0; ks<2; ++ks){
        short8 a  = *reinterpret_cast<const short8*>(Aptr  + ks*32);
        short8 b0 = *reinterpret_cast<const short8*>(Bptr0 + ks*32);
        short8 b1v= *reinterpret_cast<const short8*>(Bptr1 + ks*32);
        short8 b2 = *reinterpret_cast<const short8*>(Bptr2 + ks*32);
        short8 b3 = *reinterpret_cast<const short8*>(Bptr3 + ks*32);
        acc0 = __builtin_amdgcn_mfma_f32_16x16x32_bf16(a, b0, acc0, 0,0,0);
        acc1 = __builtin_amdgcn_mfma_f32_16x16x32_bf16(a, b1v, acc1, 0,0,0);
        acc2 = __builtin_amdgcn_mfma_f32_16x16x32_bf16(a, b2, acc2, 0,0,0);
        acc3 = __builtin_amdgcn_mfma_f32_16x16x32_bf16(a, b3, acc3, 0,0,0);
    }
    size_t rowbase = (size_t)kb*NNODE;
    float4v accs[4] = {acc0, acc1, acc2, acc3};
    #pragma unroll
    for (int nt=0; nt<4; ++nt){
        int cg2 = ncol0 + nt*16 + c16;
        #pragma unroll
        for (int r=0;r<4;r++){
            int m = m0 + quad*4 + r;
            p.yb[(rowbase + m)*DIM + cg2] = f2bu(accs[nt][r]);
        }
    }
}

__device__ __forceinline__ void st_gcn_unit(const P& p, int blk, int tid, char* smem)
{
    float* iw_s = (float*)smem;
    float (*sred)[64] = (float(*)[64])(smem + 256);
    float (*ired)[64] = (float(*)[64])(smem + 256 + 1024);
    int wave = tid>>6, lane = tid&63;
    int c16 = lane & 15, quad = lane >> 4;
    int m0 = wave*16;
    int kband = blk / (BATCH*4);
    int b = (blk/4) % BATCH;
    int nblk = blk & 3;
    int kb = kband*BATCH + b;
    if (tid < NNODE) iw_s[tid] = p.imp_w[kband*NNODE + tid];
    const ushort_t* Aptr = p.yb + ((size_t)kb*NNODE + m0 + c16)*DIM + quad*8;
    const ushort_t* Bbase = p.gwbt + (size_t)kband*DIM*DIM;
    int ncol0 = nblk*64;
    const ushort_t* Bptr0 = Bbase + (size_t)(ncol0 +  0 + c16)*DIM + quad*8;
    const ushort_t* Bptr1 = Bbase + (size_t)(ncol0 + 16 + c16)*DIM + quad*8;
    const ushort_t* Bptr2 = Bbase + (size_t)(ncol0 + 32 + c16)*DIM + quad*8;
    const ushort_t* Bptr3 = Bbase + (size_t)(ncol0 + 48 + c16)*DIM + quad*8;
    float4v acc0 = {0.f,0.f,0.f,0.f}, acc1 = acc0, acc2 = acc0, acc3 = acc0;
    #pragma unroll
    for (int ks=0; ks<8; ++ks){
        short8 a  = *reinterpret_cast<const short8*>(Aptr  + ks*32);
        short8 b0 = *reinterpret_cast<const short8*>(Bptr0 + ks*32);
        short8 b1v= *reinterpret_cast<const short8*>(Bptr1 + ks*32);
        short8 b2 = *reinterpret_cast<const short8*>(Bptr2 + ks*32);
        short8 b3 = *reinterpret_cast<const short8*>(Bptr3 + ks*32);
        acc0 = __builtin_amdgcn_mfma_f32_16x16x32_bf16(a, b0, acc0, 0,0,0);
        acc1 = __builtin_amdgcn_mfma_f32_16x16x32_bf16(a, b1v, acc1, 0,0,0);
        acc2 = __builtin_amdgcn_mfma_f32_16x16x32_bf16(a, b2, acc2, 0,0,0);
        acc3 = __builtin_amdgcn_mfma_f32_16x16x32_bf16(a, b3, acc3, 0,0,0);
    }
    __syncthreads();
    float4v accs[4] = {acc0, acc1, acc2, acc3};
    #pragma unroll
    for (int nt=0; nt<4; ++nt){
        int cg2 = ncol0 + nt*16 + c16;
        float bias = p.gb[kband*DIM + cg2];
        float v0 = accs[nt][0]+bias, v1 = accs[nt][1]+bias, v2 = accs[nt][2]+bias, v3 = accs[nt][3]+bias;
        float4 v = make_float4(v0, v1, v2, v3);
        float* dst = p.out_local + ((size_t)(b*NBANDS + kband)*DIM + cg2)*NNODE + m0 + quad*4;
        *reinterpret_cast<float4*>(dst) = v;
        int nb = m0 + quad*4;
        float s  = v0 + v1 + v2 + v3;
        float di = v0*iw_s[nb] + v1*iw_s[nb+1] + v2*iw_s[nb+2] + v3*iw_s[nb+3];
        s  += __shfl_xor(s, 16, 64);  s  += __shfl_xor(s, 32, 64);
        di += __shfl_xor(di, 16, 64); di += __shfl_xor(di, 32, 64);
        if (quad == 0){
            sred[wave][nt*16 + c16] = s;
            ired[wave][nt*16 + c16] = di;
        }
    }
    __syncthreads();
    if (tid < 64){
        float s  = sred[0][tid] + sred[1][tid] + sred[2][tid] + sred[3][tid];
        float di = ired[0][tid] + ired[1][tid] + ired[2][tid] + ired[3][tid];
        size_t o = ((size_t)b*SEQ + kband)*DIM + ncol0 + tid;
        p.scalew[o] = s * (1.f/64.f);
        p.impw[o]   = di;
    }
}

__device__ __forceinline__ void st_qkv_unit(const P& p, int u, int tid, char* smem)
{
    float* xs = (float*)smem;
    float (*part)[64] = (float(*)[64])(smem + 4096);
    int c = tid & 63, s = tid >> 6;
    int row = u / 12;
    int n0 = (u % 12) * 64;
    xs[tid] = p.scalew[(size_t)row*DIM + tid];
    __syncthreads();
    const float* wp = p.qkv_w + (size_t)(s*64)*768 + n0 + c;
    const float* xp = xs + s*64;
    float acc = 0.f;
    #pragma unroll 8
    for (int i = 0; i < 64; ++i) acc += xp[i] * wp[(size_t)i*768];
    part[s][c] = acc;
    __syncthreads();
    if (s == 0){
        p.qkvw[(size_t)row*768 + n0 + c] = p.qkv_b[n0+c] + part[0][c]+part[1][c]+part[2][c]+part[3][c];
    }
}

__device__ __forceinline__ void st_projattn_unit(const P& p, int u, int tid, char* smem)
{
    float* xs = (float*)smem;
    float (*part)[64] = (float(*)[64])(smem + 1024);
    int h = tid >> 6, l = tid & 63;
    int c = tid & 63, s = tid >> 6;
    int row = u / 4;
    int n0 = (u % 4) * 64;
    int b = row / SEQ, i = row % SEQ;
    const float* base = p.qkvw + (size_t)b*SEQ*3*DIM;
    float qv = base[(size_t)i*3*DIM + h*DHEAD + l];
    float pj[SEQ];
    #pragma unroll
    for (int j=0;j<SEQ;j++){
        float pr = qv * base[(size_t)j*3*DIM + DIM + h*DHEAD + l];
        for (int o=32;o>0;o>>=1) pr += __shfl_xor(pr,o,64);
        pj[j] = pr * 0.125f;
    }
    float m = pj[0];
    #pragma unroll
    for (int j=1;j<SEQ;j++) m = fmaxf(m, pj[j]);
    float ssum = 0.f;
    #pragma unroll
    for (int j=0;j<SEQ;j++){ pj[j] = __expf(pj[j]-m); ssum += pj[j]; }
    float inv = 1.f/ssum;
    float o = 0.f;
    #pragma unroll
    for (int j=0;j<SEQ;j++) o += pj[j]*inv * base[(size_t)j*3*DIM + 2*DIM + h*DHEAD + l];
    xs[tid] = o;
    __syncthreads();
    const float* wp = p.attn_ow + (size_t)(s*64)*DIM + n0 + c;
    const float* xp = xs + s*64;
    float acc = 0.f;
    #pragma unroll 8
    for (int k=0;k<64;++k) acc += xp[k] * wp[(size_t)k*DIM];
    part[s][c] = acc;
    __syncthreads();
    if (s == 0){
        p.projw[(size_t)row*DIM + n0 + c] = p.attn_ob[n0+c] + part[0][c]+part[1][c]+part[2][c]+part[3][c];
    }
}

__device__ __forceinline__ void st_mlp1_unit(const P& p, int u, int tid, char* smem)
{
    float* xs = (float*)smem;
    float* red = (float*)(smem + 1024);
    float (*part)[64] = (float(*)[64])(smem + 1024 + 16);
    int c = tid & 63, s = tid >> 6;
    int row = u / 16;
    int n0 = (u % 16) * 64;
    float v = p.projw[(size_t)row*DIM + tid] + p.scalew[(size_t)row*DIM + tid];
    float h = block_ln(v, tid, red, p.ln1_g[tid], p.ln1_b[tid]);
    xs[tid] = h;
    if ((u % 16) == 0) p.h1w[(size_t)row*DIM + tid] = h;
    __syncthreads();
    const float* wp = p.mlp_w1 + (size_t)(s*64)*1024 + n0 + c;
    const float* xp = xs + s*64;
    float acc = 0.f;
    #pragma unroll 8
    for (int i=0;i<64;++i) acc += xp[i] * wp[(size_t)i*1024];
    part[s][c] = acc;
    __syncthreads();
    if (s == 0){
        float o = p.mlp_b1[n0+c] + part[0][c] + part[1][c] + part[2][c] + part[3][c];
        o = 0.5f*o*(1.f + erff(o*0.70710678118654752f));
        p.mhw[(size_t)row*1024 + n0 + c] = o;
    }
}

__device__ __forceinline__ void st_mlp2_unit(const P& p, int u, int tid, char* smem)
{
    float* xs = (float*)smem;
    float (*part)[32] = (float(*)[32])(smem + 4096);
    int c = tid & 31, s = tid >> 5;
    int row = u / 8;
    int n0 = (u % 8) * 32;
    for (int i = tid; i < 1024; i += 256) xs[i] = p.mhw[(size_t)row*1024 + i];
    __syncthreads();
    const float* wp = p.mlp_w2 + (size_t)(s*128)*DIM + n0 + c;
    const float* xp = xs + s*128;
    float acc = 0.f;
    #pragma unroll 8
    for (int i=0;i<128;++i) acc += xp[i] * wp[(size_t)i*DIM];
    part[s][c] = acc;
    __syncthreads();
    if (s == 0){
        float v = p.mlp_b2[n0+c];
        #pragma unroll
        for (int q=0;q<8;q++) v += part[q][c];
        p.m2w[(size_t)row*DIM + n0 + c] = v;
    }
}

__device__ __forceinline__ void st_gab_unit(const P& p, int u, int tid, char* smem)
{
    float* xs = (float*)smem;
    float* red = (float*)(smem + 1024);
    float (*partA)[64] = (float(*)[64])(smem + 1024 + 16);
    float (*partB)[64] = (float(*)[64])(smem + 1024 + 16 + 1024);
    int c = tid & 63, s = tid >> 6;
    int row = u / 4;
    int n0 = (u % 4) * 64;
    float v = p.m2w[(size_t)row*DIM + tid] + p.h1w[(size_t)row*DIM + tid];
    float h = block_ln(v, tid, red, p.ln2_g[tid], p.ln2_b[tid]);
    xs[tid] = h;
    if ((u % 4) == 0) p.sew[(size_t)row*DIM + tid] = h;
    __syncthreads();
    const float* wpA = p.g_sim_w1 + (size_t)(s*64)*DIM + n0 + c;
    const float* wpB = wpA + (size_t)DIM*DIM;
    const float* xp = xs + s*64;
    float aA = 0.f, aB = 0.f;
    #pragma unroll 8
    for (int i=0;i<64;++i){
        float xv = xp[i];
        aA += xv * wpA[(size_t)i*DIM];
        aB += xv * wpB[(size_t)i*DIM];
    }
    partA[s][c] = aA;
    partB[s][c] = aB;
    __syncthreads();
    if (s == 0){
        p.gaw[(size_t)row*DIM + n0 + c] = p.g_sim_b1[n0+c] + partA[0][c]+partA[1][c]+partA[2][c]+partA[3][c];
        p.gbw[(size_t)row*DIM + n0 + c] = partB[0][c]+partB[1][c]+partB[2][c]+partB[3][c];
    }
}

__device__ __forceinline__ void st_goutfin_unit(const P& p, int u, int tid, char* smem)
{
    float* dyn_s = (float*)smem;
    float* xs = (float*)(smem + 64);
    float (*part)[64] = (float(*)[64])(smem + 64 + 1024);
    int wave = tid >> 6, lane = tid & 63;
    int c = tid & 63, s = tid >> 6;
    int row = u / 4;
    int n0 = (u % 4) * 64;
    int b = row / SEQ, i = row % SEQ;
    for (int j = wave; j < SEQ; j += 4){
        const float* gar = p.gaw + (size_t)row*DIM;
        const float* gbr = p.gbw + ((size_t)b*SEQ + j)*DIM;
        float acc = 0.f;
        #pragma unroll
        for (int m=0;m<4;m++){
            int dd = lane + m*64;
            float v = gar[dd] + gbr[dd];
            float e = (v>0.f) ? v : (__expf(v)-1.f);
            acc += e * p.g_sim_w2[dd];
        }
        for (int o=32;o>0;o>>=1) acc += __shfl_xor(acc,o,64);
        if (lane==0) dyn_s[j] = acc;
    }
    __syncthreads();
    float gc[SEQ];
    {
        float sb2 = p.g_sim_b2[0];
        float m = -1e30f;
        #pragma unroll
        for (int j=0;j<SEQ;j++){
            float sg = 1.f/(1.f+__expf(-(dyn_s[j]+sb2)));
            gc[j] = p.gbase[i*SEQ+j] + sg;
            m = fmaxf(m, gc[j]);
        }
        float ssum=0.f;
        #pragma unroll
        for (int j=0;j<SEQ;j++){ gc[j]=__expf(gc[j]-m); ssum+=gc[j]; }
        float inv = 1.f/ssum;
        #pragma unroll
        for (int j=0;j<SEQ;j++) gc[j] *= inv;
    }
    if (n0 == 0 && tid < SEQ) p.out_gadj[((size_t)b*SEQ+i)*SEQ + tid] = gc[tid];
    float t = 0.f;
    #pragma unroll
    for (int j=0;j<SEQ;j++) t += gc[j]*p.sew[((size_t)b*SEQ + j)*DIM + tid];
    xs[tid] = t;
    __syncthreads();
    const float* wp = p.g_gcn_w + (size_t)(s*64)*DIM + n0 + c;
    const float* xp = xs + s*64;
    float acc = 0.f;
    #pragma unroll 8
    for (int k=0;k<64;++k) acc += xp[k] * wp[(size_t)k*DIM];
    part[s][c] = acc;
    __syncthreads();
    if (s == 0){
        float g = p.g_gcn_b[n0+c] + part[0][c]+part[1][c]+part[2][c]+part[3][c];
        size_t o = (size_t)row*DIM + n0 + c;
        p.out0[o] = g * p.impw[o] + p.imp_b[i];
    }
}

// ======================= mega (cooperative) ================================
__global__ void __launch_bounds__(256) k_mega(P p)
{
    cg::grid_group grid = cg::this_grid();
    __shared__ __align__(16) char smem[38400];
    int tid = threadIdx.x;
    const int G = gridDim.x;

    for (int blk = blockIdx.x; blk < 641; blk += G){ st_head_unit(p, blk, tid, smem); __syncthreads(); }
    grid.sync();
    for (int blk = blockIdx.x; blk < 640; blk += G){ st_ab_unit(p, blk, tid); }
    grid.sync();
    for (int blk = blockIdx.x; blk < 1280; blk += G){ st_dyn_unit(p, blk, tid, smem); __syncthreads(); }
    grid.sync();
    for (int blk = blockIdx.x; blk < 320; blk += G){ st_y_unit(p, blk, tid); }
    grid.sync();
    for (int blk = blockIdx.x; blk < 320; blk += G){ st_gcn_unit(p, blk, tid, smem); __syncthreads(); }
    grid.sync();
    for (int u = blockIdx.x; u < 960; u += G){ st_qkv_unit(p, u, tid, smem); __syncthreads(); }
    grid.sync();
    for (int u = blockIdx.x; u < 320; u += G){ st_projattn_unit(p, u, tid, smem); __syncthreads(); }
    grid.sync();
    for (int u = blockIdx.x; u < 1280; u += G){ st_mlp1_unit(p, u, tid, smem); __syncthreads(); }
    grid.sync();
    for (int u = blockIdx.x; u < 640; u += G){ st_mlp2_unit(p, u, tid, smem); __syncthreads(); }
    grid.sync();
    for (int u = blockIdx.x; u < 320; u += G){ st_gab_unit(p, u, tid, smem); __syncthreads(); }
    grid.sync();
    for (int u = blockIdx.x; u < 320; u += G){ st_goutfin_unit(p, u, tid, smem); __syncthreads(); }
}

// ======================= fallback kernels (one stage each) =================
__global__ void __launch_bounds__(256) k_f_head(P p){ __shared__ __align__(16) char smem[38400]; st_head_unit(p, blockIdx.x, threadIdx.x, smem); }
__global__ void __launch_bounds__(256) k_f_ab(P p){ st_ab_unit(p, blockIdx.x, threadIdx.x); }
__global__ void __launch_bounds__(256) k_f_dyn(P p){ __shared__ __align__(16) char smem[38400]; st_dyn_unit(p, blockIdx.x, threadIdx.x, smem); }
__global__ void __launch_bounds__(256) k_f_y(P p){ st_y_unit(p, blockIdx.x, threadIdx.x); }
__global__ void __launch_bounds__(256) k_f_gcn(P p){ __shared__ __align__(16) char smem[38400]; st_gcn_unit(p, blockIdx.x, threadIdx.x, smem); }
__global__ void __launch_bounds__(256) k_f_qkv(P p){ __shared__ __align__(16) char smem[38400]; st_qkv_unit(p, blockIdx.x, threadIdx.x, smem); }
__global__ void __launch_bounds__(256) k_f_projattn(P p){ __shared__ __align__(16) char smem[38400]; st_projattn_unit(p, blockIdx.x, threadIdx.x, smem); }
__global__ void __launch_bounds__(256) k_f_mlp1(P p){ __shared__ __align__(16) char smem[38400]; st_mlp1_unit(p, blockIdx.x, threadIdx.x, smem); }
__global__ void __launch_bounds__(256) k_f_mlp2(P p){ __shared__ __align__(16) char smem[38400]; st_mlp2_unit(p, blockIdx.x, threadIdx.x, smem); }
__global__ void __launch_bounds__(256) k_f_gab(P p){ __shared__ __align__(16) char smem[38400]; st_gab_unit(p, blockIdx.x, threadIdx.x, smem); }
__global__ void __launch_bounds__(256) k_f_goutfin(P p){ __shared__ __align__(16) char smem[38400]; st_goutfin_unit(p, blockIdx.x, threadIdx.x, smem); }

extern "C" void kernel_launch(void* const* d_in, const int* in_sizes, int n_in,
                              void* d_out, int out_size, void* d_ws, size_t ws_size,
                              hipStream_t stream)
{
    P prm;
    prm.l_adj_w   = (const float*)d_in[1];
    prm.w1        = (const float*)d_in[2];
    prm.b1        = (const float*)d_in[3];
    prm.w2        = (const float*)d_in[4];
    prm.b2arr     = (const float*)d_in[5];
    prm.l_pf      = (const float*)d_in[6];
    prm.l_pos_enc = (const float*)d_in[7];
    prm.gw        = (const float*)d_in[8];
    prm.gb        = (const float*)d_in[9];
    prm.g_adj_w   = (const float*)d_in[10];
    prm.g_sim_w1  = (const float*)d_in[11];
    prm.g_sim_b1  = (const float*)d_in[12];
    prm.g_sim_w2  = (const float*)d_in[13];
    prm.g_sim_b2  = (const float*)d_in[14];
    prm.g_pf      = (const float*)d_in[15];
    prm.g_pos_enc = (const float*)d_in[16];
    prm.g_gcn_w   = (const float*)d_in[17];
    prm.g_gcn_b   = (const float*)d_in[18];
    prm.qkv_w     = (const float*)d_in[19];
    prm.qkv_b     = (const float*)d_in[20];
    prm.attn_ow   = (const float*)d_in[21];
    prm.attn_ob   = (const float*)d_in[22];
    prm.ln1_g     = (const float*)d_in[23];
    prm.ln1_b     = (const float*)d_in[24];
    prm.ln2_g     = (const float*)d_in[25];
    prm.ln2_b     = (const float*)d_in[26];
    prm.mlp_w1    = (const float*)d_in[27];
    prm.mlp_b1    = (const float*)d_in[28];
    prm.mlp_w2    = (const float*)d_in[29];
    prm.mlp_b2    = (const float*)d_in[30];
    prm.imp_w     = (const float*)d_in[31];
    prm.imp_b     = (const float*)d_in[32];
    prm.feat      = (const float*)d_in[0];

    prm.out0      = (float*)d_out;
    prm.out_gadj  = prm.out0 + (size_t)BATCH*NBANDS*DIM;
    prm.out_local = prm.out_gadj + (size_t)BATCH*NBANDS*NBANDS;

    const size_t BIG = (size_t)NBANDS*BATCH*NNODE*DIM;           // 1,310,720 elems
    prm.xtb   = (ushort_t*)d_ws;
    prm.aab   = prm.xtb + BIG;
    prm.bbb   = prm.aab + BIG;
    prm.xtT   = prm.bbb + BIG;
    prm.yb    = prm.aab;                                          // reuse: aab dead after dyn
    prm.w1bt  = prm.xtT + BIG;
    prm.gwbt  = prm.w1bt + (size_t)NBANDS*512*DIM;
    prm.combb = prm.gwbt + (size_t)NBANDS*DIM*DIM;
    float* fp = (float*)(prm.combb + (size_t)NBANDS*BATCH*NNODE*NNODE);
    prm.sbase  = fp; fp += NBANDS*NNODE*NNODE;
    prm.gbase  = fp; fp += 32;
    prm.scalew = fp; fp += BATCH*SEQ*DIM;
    prm.impw   = fp; fp += BATCH*SEQ*DIM;
    prm.qkvw   = fp; fp += BATCH*SEQ*3*DIM;
    prm.projw  = fp; fp += BATCH*SEQ*DIM;
    prm.h1w    = fp; fp += BATCH*SEQ*DIM;
    prm.mhw    = fp; fp += BATCH*SEQ*4*DIM;
    prm.m2w    = fp; fp += BATCH*SEQ*DIM;
    prm.sew    = fp; fp += BATCH*SEQ*DIM;
    prm.gaw    = fp; fp += BATCH*SEQ*DIM;
    prm.gbw    = fp; fp += BATCH*SEQ*DIM;

    void* kargs[] = { (void*)&prm };
    hipError_t cerr = hipLaunchCooperativeKernel((const void*)k_mega, dim3(256), dim3(256),
                                                 kargs, 0, stream);
    if (cerr != hipSuccess){
        (void)hipGetLastError();   // clear sticky error, run sequential fallback
        k_f_head<<<641, 256, 0, stream>>>(prm);
        k_f_ab<<<640, 256, 0, stream>>>(prm);
        k_f_dyn<<<1280, 256, 0, stream>>>(prm);
        k_f_y<<<320, 256, 0, stream>>>(prm);
        k_f_gcn<<<320, 256, 0, stream>>>(prm);
        k_f_qkv<<<960, 256, 0, stream>>>(prm);
        k_f_projattn<<<320, 256, 0, stream>>>(prm);
        k_f_mlp1<<<1280, 256, 0, stream>>>(prm);
        k_f_mlp2<<<640, 256, 0, stream>>>(prm);
        k_f_gab<<<320, 256, 0, stream>>>(prm);
        k_f_goutfin<<<320, 256, 0, stream>>>(prm);
    }
}

// Round 11
// 321.133 us; speedup vs baseline: 1.8439x; 1.8439x over previous
//
#include <hip/hip_runtime.h>
#include <hip/hip_bf16.h>

#define NBANDS 5
#define BATCH  16
#define DIM    256
#define NNODE  64
#define SEQ    5
#define NHEAD  4
#define DHEAD  64

typedef __hip_bfloat16 bf16;
typedef unsigned short ushort_t;
typedef __attribute__((ext_vector_type(8))) short short8;   // 8 bf16 (4 VGPRs)
typedef __attribute__((ext_vector_type(4))) float float4v;  // 4 fp32 acc

__device__ __forceinline__ float bu2f(ushort_t u){
    bf16 h = *reinterpret_cast<bf16*>(&u);
    return __bfloat162float(h);
}
__device__ __forceinline__ ushort_t f2bu(float x){
    bf16 h = __float2bfloat16(x);
    return *reinterpret_cast<ushort_t*>(&h);
}

// ============ k_head: bases + MFMA weight prep + feature transpose ============
__global__ void __launch_bounds__(256) k_head(
    const float* __restrict__ l_adj_w, const float* __restrict__ l_pos_enc,
    const float* __restrict__ l_pf,
    const float* __restrict__ g_adj_w, const float* __restrict__ g_pos_enc,
    const float* __restrict__ g_pf,
    float* __restrict__ sbase, float* __restrict__ gbase,
    const float* __restrict__ w1, const float* __restrict__ gw,
    ushort_t* __restrict__ w1bt, ushort_t* __restrict__ gwbt,
    const float* __restrict__ feat,
    ushort_t* __restrict__ xtb, ushort_t* __restrict__ xtT)
{
    int blk = blockIdx.x;
    int tid = threadIdx.x;
    __shared__ ushort_t tile[64][65];

    if (blk < 80) {
        int r = blk*4 + (tid>>6);
        int k = r >> 6, i = r & 63;
        int t = tid & 63;
        float aw = l_adj_w[(k*NNODE + i)*NNODE + t];
        float pe = l_pos_enc[(k*NNODE + i)*NNODE + t];
        float m1 = aw, m2 = pe;
        for (int o=32;o>0;o>>=1){ m1 = fmaxf(m1, __shfl_xor(m1,o,64)); m2 = fmaxf(m2, __shfl_xor(m2,o,64)); }
        float e1 = __expf(aw-m1), e2 = __expf(pe-m2);
        float s1=e1, s2=e2;
        for (int o=32;o>0;o>>=1){ s1 += __shfl_xor(s1,o,64); s2 += __shfl_xor(s2,o,64); }
        float pf = l_pf[k];
        sbase[(k*NNODE+i)*NNODE + t] = e1/s1 + pf*(e2/s2);
    } else if (blk == 80) {
        if (tid < NBANDS) {
            int i = tid;
            float r1[NBANDS], r2[NBANDS];
            float m1=-1e30f, m2=-1e30f;
            for (int j=0;j<NBANDS;j++){
                r1[j]=g_adj_w[i*NBANDS+j]; r2[j]=g_pos_enc[i*NBANDS+j];
                m1=fmaxf(m1,r1[j]); m2=fmaxf(m2,r2[j]);
            }
            float s1=0.f,s2=0.f;
            for (int j=0;j<NBANDS;j++){ r1[j]=__expf(r1[j]-m1); r2[j]=__expf(r2[j]-m2); s1+=r1[j]; s2+=r2[j]; }
            float pf = g_pf[0];
            for (int j=0;j<NBANDS;j++) gbase[i*NBANDS+j] = r1[j]/s1 + pf*(r2[j]/s2);
        }
    } else if (blk < 321) {
        int idx = blk - 81;
        int inst = idx >> 4;
        int t = idx & 15;
        int r0 = (t>>2)*64, c0 = (t&3)*64;
        const float* src; ushort_t* dst;
        if (inst < 10){
            int k = inst>>1, half = inst&1;
            src = w1  + ((size_t)k*512 + half*256)*256;
            dst = w1bt+ ((size_t)k*512 + half*256)*256;
        } else {
            int k = inst-10;
            src = gw  + (size_t)k*65536;
            dst = gwbt+ (size_t)k*65536;
        }
        int jj = tid & 63, i4 = tid >> 6;
        for (int p=0;p<16;p++){
            int i = p*4 + i4;
            tile[i][jj] = f2bu(src[(size_t)(r0+i)*256 + c0 + jj]);
        }
        __syncthreads();
        for (int p=0;p<16;p++){
            int i = p*4 + i4;
            dst[(size_t)(c0+i)*256 + r0 + jj] = tile[jj][i];
        }
    } else {
        int idx = blk - 321;                   // (k,b,dt)
        int k = idx >> 6;
        int b = (idx >> 2) & 15;
        int dt = idx & 3;
        const float* src = feat + ((size_t)b*NBANDS*DIM + (size_t)k*DIM)*NNODE; // [D][N]
        ushort_t* dst = xtb + (size_t)(k*BATCH+b)*NNODE*DIM;                    // [N][D]
        ushort_t* dstT = xtT + (size_t)(k*BATCH+b)*DIM*NNODE;                   // [D][N]
        for (int u=0; u<16; ++u){
            int i = dt*4096 + u*256 + tid;
            dstT[i] = f2bu(src[i]);
        }
        for (int r=0;r<16;r++){
            int dp = r*4 + (tid>>6);
            int n  = tid & 63;
            tile[dp][n] = f2bu(src[(size_t)(dt*64+dp)*NNODE + n]);
        }
        __syncthreads();
        for (int r=0;r<16;r++){
            int n  = r*4 + (tid>>6);
            int dp = tid & 63;
            dst[(size_t)n*DIM + dt*64 + dp] = tile[dp][n];
        }
    }
}

// ---- MFMA a/bp: per band GEMM [1024 x 256] @ [256 x 512] -> aab|bbb bf16 ----
__global__ void __launch_bounds__(256) k_ab_mfma(const ushort_t* __restrict__ xtb,
                        const ushort_t* __restrict__ w1bt, const float* __restrict__ b1,
                        ushort_t* __restrict__ aab, ushort_t* __restrict__ bbb)
{
    int blk = blockIdx.x;                 // 5*16*8
    int kband = blk / (BATCH*8);
    int b = (blk/8) % BATCH;
    int nblk = blk & 7;
    int tid = threadIdx.x;
    int wave = tid>>6, lane = tid&63;
    int c16 = lane & 15, quad = lane >> 4;
    int m0 = wave*16;
    size_t rowbase = (size_t)(kband*BATCH+b)*NNODE;
    const ushort_t* Aptr = xtb + (rowbase + m0 + c16)*DIM + quad*8;
    const ushort_t* Bbase = w1bt + (size_t)kband*512*DIM;
    int ncol0 = nblk*64;
    const ushort_t* Bptr0 = Bbase + (size_t)(ncol0 +  0 + c16)*DIM + quad*8;
    const ushort_t* Bptr1 = Bbase + (size_t)(ncol0 + 16 + c16)*DIM + quad*8;
    const ushort_t* Bptr2 = Bbase + (size_t)(ncol0 + 32 + c16)*DIM + quad*8;
    const ushort_t* Bptr3 = Bbase + (size_t)(ncol0 + 48 + c16)*DIM + quad*8;
    float4v acc0 = {0.f,0.f,0.f,0.f}, acc1 = acc0, acc2 = acc0, acc3 = acc0;
    #pragma unroll
    for (int ks=0; ks<8; ++ks){
        short8 a  = *reinterpret_cast<const short8*>(Aptr  + ks*32);
        short8 b0 = *reinterpret_cast<const short8*>(Bptr0 + ks*32);
        short8 b1v= *reinterpret_cast<const short8*>(Bptr1 + ks*32);
        short8 b2 = *reinterpret_cast<const short8*>(Bptr2 + ks*32);
        short8 b3 = *reinterpret_cast<const short8*>(Bptr3 + ks*32);
        acc0 = __builtin_amdgcn_mfma_f32_16x16x32_bf16(a, b0, acc0, 0,0,0);
        acc1 = __builtin_amdgcn_mfma_f32_16x16x32_bf16(a, b1v, acc1, 0,0,0);
        acc2 = __builtin_amdgcn_mfma_f32_16x16x32_bf16(a, b2, acc2, 0,0,0);
        acc3 = __builtin_amdgcn_mfma_f32_16x16x32_bf16(a, b3, acc3, 0,0,0);
    }
    int half = nblk >> 2;
    int cbase = (nblk & 3)*64;
    ushort_t* dst = half ? bbb : aab;
    float4v accs[4] = {acc0, acc1, acc2, acc3};
    #pragma unroll
    for (int nt=0; nt<4; ++nt){
        int cg = cbase + nt*16 + c16;
        float bias = half ? 0.f : b1[kband*DIM + cg];
        #pragma unroll
        for (int r=0;r<4;r++){
            int m = m0 + quad*4 + r;
            dst[(rowbase + m)*DIM + cg] = f2bu(accs[nt][r] + bias);
        }
    }
}

// ------- dyn+comb: lane j owns pair (i,j); b-tile staged in LDS -------------
__global__ void __launch_bounds__(256) k_dyn_comb(const ushort_t* __restrict__ aab,
                           const ushort_t* __restrict__ bbb,
                           const float* __restrict__ w2, const float* __restrict__ b2arr,
                           const float* __restrict__ sbase,
                           ushort_t* __restrict__ combb)
{
    int blk = blockIdx.x;                     // 5*16*16 blocks, 4 i-rows each
    int k = blk / (BATCH*16);
    int b = (blk / 16) % BATCH;
    int i0 = (blk % 16) * 4;
    int kb = k*BATCH + b;
    __shared__ ushort_t bs[64][260];
    __shared__ float arows[4][DIM];
    __shared__ float w2s[DIM];
    int tid = threadIdx.x;
    int wave = tid >> 6, lane = tid & 63;
    const ushort_t* bsrc = bbb + (size_t)kb*NNODE*DIM;
    for (int u=0; u<16; ++u){
        int idx = u*1024 + tid*4;
        int row = idx >> 8, col = idx & 255;
        *reinterpret_cast<ushort4*>(&bs[row][col]) =
            *reinterpret_cast<const ushort4*>(&bsrc[(size_t)row*DIM + col]);
    }
    for (int r=0;r<4;r++) arows[r][tid] = bu2f(aab[((size_t)kb*NNODE + i0 + r)*DIM + tid]);
    w2s[tid] = w2[k*DIM + tid];
    __syncthreads();

    int i = i0 + wave;
    float acc = 0.f;
    #pragma unroll 4
    for (int dd=0; dd<64; ++dd){
        ushort4 bv = *reinterpret_cast<const ushort4*>(&bs[lane][dd*4]);
        float4 av = *reinterpret_cast<const float4*>(&arows[wave][dd*4]);
        float4 wv = *reinterpret_cast<const float4*>(&w2s[dd*4]);
        float v0 = av.x + bu2f(bv.x);
        float v1 = av.y + bu2f(bv.y);
        float v2 = av.z + bu2f(bv.z);
        float v3 = av.w + bu2f(bv.w);
        float e0 = (v0>0.f)? v0 : (__expf(v0)-1.f);
        float e1 = (v1>0.f)? v1 : (__expf(v1)-1.f);
        float e2 = (v2>0.f)? v2 : (__expf(v2)-1.f);
        float e3 = (v3>0.f)? v3 : (__expf(v3)-1.f);
        acc += e0*wv.x + e1*wv.y + e2*wv.z + e3*wv.w;
    }
    float sb2 = b2arr[k];
    float sg = 1.f/(1.f + __expf(-(acc + sb2)));
    float val = sbase[(k*NNODE + i)*NNODE + lane] + sg;
    float m = val;
    for (int o=32;o>0;o>>=1) m = fmaxf(m, __shfl_xor(m,o,64));
    float e = __expf(val - m);
    float s = e;
    for (int o=32;o>0;o>>=1) s += __shfl_xor(s,o,64);
    combb[((size_t)kb*NNODE + i)*NNODE + lane] = f2bu(e/s);
}

// ---- MFMA y: per (k,b) GEMM [64 x 64] @ [64 x 256] -> yb bf16 [kb][n][d] ----
__global__ void __launch_bounds__(256) k_y_mfma(const ushort_t* __restrict__ combb,
                       const ushort_t* __restrict__ xtT,
                       ushort_t* __restrict__ yb)
{
    int blk = blockIdx.x;                 // 5*16*4
    int kband = blk / (BATCH*4);
    int b = (blk/4) % BATCH;
    int nblk = blk & 3;
    int tid = threadIdx.x;
    int wave = tid>>6, lane = tid&63;
    int c16 = lane & 15, quad = lane >> 4;
    int m0 = wave*16;
    int kb = kband*BATCH + b;
    const ushort_t* Aptr = combb + ((size_t)kb*NNODE + m0 + c16)*NNODE + quad*8;  // [n][j]
    const ushort_t* Bbase = xtT + (size_t)kb*DIM*NNODE;                            // [d][j]
    int ncol0 = nblk*64;
    const ushort_t* Bptr0 = Bbase + (size_t)(ncol0 +  0 + c16)*NNODE + quad*8;
    const ushort_t* Bptr1 = Bbase + (size_t)(ncol0 + 16 + c16)*NNODE + quad*8;
    const ushort_t* Bptr2 = Bbase + (size_t)(ncol0 + 32 + c16)*NNODE + quad*8;
    const ushort_t* Bptr3 = Bbase + (size_t)(ncol0 + 48 + c16)*NNODE + quad*8;
    float4v acc0 = {0.f,0.f,0.f,0.f}, acc1 = acc0, acc2 = acc0, acc3 = acc0;
    #pragma unroll
    for (int ks=0; ks<2; ++ks){
        short8 a  = *reinterpret_cast<const short8*>(Aptr  + ks*32);
        short8 b0 = *reinterpret_cast<const short8*>(Bptr0 + ks*32);
        short8 b1v= *reinterpret_cast<const short8*>(Bptr1 + ks*32);
        short8 b2 = *reinterpret_cast<const short8*>(Bptr2 + ks*32);
        short8 b3 = *reinterpret_cast<const short8*>(Bptr3 + ks*32);
        acc0 = __builtin_amdgcn_mfma_f32_16x16x32_bf16(a, b0, acc0, 0,0,0);
        acc1 = __builtin_amdgcn_mfma_f32_16x16x32_bf16(a, b1v, acc1, 0,0,0);
        acc2 = __builtin_amdgcn_mfma_f32_16x16x32_bf16(a, b2, acc2, 0,0,0);
        acc3 = __builtin_amdgcn_mfma_f32_16x16x32_bf16(a, b3, acc3, 0,0,0);
    }
    size_t rowbase = (size_t)kb*NNODE;
    float4v accs[4] = {acc0, acc1, acc2, acc3};
    #pragma unroll
    for (int nt=0; nt<4; ++nt){
        int cg = ncol0 + nt*16 + c16;
        #pragma unroll
        for (int r=0;r<4;r++){
            int m = m0 + quad*4 + r;
            yb[(rowbase + m)*DIM + cg] = f2bu(accs[nt][r]);
        }
    }
}

// ==== k_gcn_qkv: full-row gcn MFMA + out_local + scale/imp + qkv epilogue ====
// block = (kband, b); waves own 64-col chunks; loop 4 row-tiles of n
__global__ void __launch_bounds__(256) k_gcn_qkv(const ushort_t* __restrict__ yb,
                        const ushort_t* __restrict__ gwbt, const float* __restrict__ gb,
                        const float* __restrict__ imp_w,
                        const float* __restrict__ qkv_w, const float* __restrict__ qkv_b,
                        float* __restrict__ out_local,
                        float* __restrict__ scalew, float* __restrict__ impw,
                        float* __restrict__ qkvw)
{
    int blk = blockIdx.x;                 // 80 = 5*16
    int kband = blk / BATCH;
    int b = blk % BATCH;
    int kb = kband*BATCH + b;
    int tid = threadIdx.x;
    int wave = tid>>6, lane = tid&63;
    int c16 = lane & 15, quad = lane >> 4;
    int ncol0 = wave*64;
    __shared__ float iw_s[NNODE];
    __shared__ float s_lds[DIM];
    if (tid < NNODE) iw_s[tid] = imp_w[kband*NNODE + tid];
    __syncthreads();

    const ushort_t* Bbase = gwbt + (size_t)kband*DIM*DIM;     // [col][kk]
    const ushort_t* Bptr0 = Bbase + (size_t)(ncol0 +  0 + c16)*DIM + quad*8;
    const ushort_t* Bptr1 = Bbase + (size_t)(ncol0 + 16 + c16)*DIM + quad*8;
    const ushort_t* Bptr2 = Bbase + (size_t)(ncol0 + 32 + c16)*DIM + quad*8;
    const ushort_t* Bptr3 = Bbase + (size_t)(ncol0 + 48 + c16)*DIM + quad*8;

    float sacc[4] = {0.f,0.f,0.f,0.f};
    float dacc[4] = {0.f,0.f,0.f,0.f};

    for (int rt=0; rt<4; ++rt){
        const ushort_t* Aptr = yb + ((size_t)kb*NNODE + rt*16 + c16)*DIM + quad*8;  // [n][d]
        float4v acc0 = {0.f,0.f,0.f,0.f}, acc1 = acc0, acc2 = acc0, acc3 = acc0;
        #pragma unroll
        for (int ks=0; ks<8; ++ks){
            short8 a  = *reinterpret_cast<const short8*>(Aptr  + ks*32);
            short8 b0 = *reinterpret_cast<const short8*>(Bptr0 + ks*32);
            short8 b1v= *reinterpret_cast<const short8*>(Bptr1 + ks*32);
            short8 b2 = *reinterpret_cast<const short8*>(Bptr2 + ks*32);
            short8 b3 = *reinterpret_cast<const short8*>(Bptr3 + ks*32);
            acc0 = __builtin_amdgcn_mfma_f32_16x16x32_bf16(a, b0, acc0, 0,0,0);
            acc1 = __builtin_amdgcn_mfma_f32_16x16x32_bf16(a, b1v, acc1, 0,0,0);
            acc2 = __builtin_amdgcn_mfma_f32_16x16x32_bf16(a, b2, acc2, 0,0,0);
            acc3 = __builtin_amdgcn_mfma_f32_16x16x32_bf16(a, b3, acc3, 0,0,0);
        }
        float4v accs[4] = {acc0, acc1, acc2, acc3};
        #pragma unroll
        for (int nt=0; nt<4; ++nt){
            int cg = ncol0 + nt*16 + c16;
            float bias = gb[kband*DIM + cg];
            float v0 = accs[nt][0]+bias, v1 = accs[nt][1]+bias,
                  v2 = accs[nt][2]+bias, v3 = accs[nt][3]+bias;
            float4 v = make_float4(v0, v1, v2, v3);
            float* dst = out_local + ((size_t)(b*NBANDS + kband)*DIM + cg)*NNODE + rt*16 + quad*4;
            *reinterpret_cast<float4*>(dst) = v;
            int nb = rt*16 + quad*4;
            sacc[nt] += v0 + v1 + v2 + v3;
            dacc[nt] += v0*iw_s[nb] + v1*iw_s[nb+1] + v2*iw_s[nb+2] + v3*iw_s[nb+3];
        }
    }
    size_t row = (size_t)b*SEQ + kband;
    #pragma unroll
    for (int nt=0; nt<4; ++nt){
        float s = sacc[nt], d = dacc[nt];
        s += __shfl_xor(s, 16, 64);  s += __shfl_xor(s, 32, 64);
        d += __shfl_xor(d, 16, 64);  d += __shfl_xor(d, 32, 64);
        if (quad == 0){
            int cg = ncol0 + nt*16 + c16;
            float sv = s * (1.f/64.f);
            scalew[row*DIM + cg] = sv;
            impw[row*DIM + cg]   = d;
            s_lds[cg] = sv;
        }
    }
    __syncthreads();
    // qkv epilogue: thread computes cols tid, tid+256, tid+512
    float a0 = 0.f, a1 = 0.f, a2 = 0.f;
    for (int kk=0; kk<DIM; ++kk){
        float x = s_lds[kk];
        const float* wp = qkv_w + (size_t)kk*768;
        a0 += x * wp[tid];
        a1 += x * wp[256 + tid];
        a2 += x * wp[512 + tid];
    }
    qkvw[row*768 + tid]       = a0 + qkv_b[tid];
    qkvw[row*768 + 256 + tid] = a1 + qkv_b[256 + tid];
    qkvw[row*768 + 512 + tid] = a2 + qkv_b[512 + tid];
}

// ---------------- block LayerNorm over 256 elems ----------------------------
__device__ __forceinline__ float block_ln(float v, int tid, float* red, float g, float bln)
{
    float s = v;
    for (int o=32;o>0;o>>=1) s += __shfl_xor(s,o,64);
    int wave = tid>>6, lane = tid&63;
    if (lane==0) red[wave] = s;
    __syncthreads();
    float mean = (red[0]+red[1]+red[2]+red[3]) * (1.f/DIM);
    float c = v - mean;
    float q = c*c;
    for (int o=32;o>0;o>>=1) q += __shfl_xor(q,o,64);
    __syncthreads();
    if (lane==0) red[wave] = q;
    __syncthreads();
    float var = (red[0]+red[1]+red[2]+red[3]) * (1.f/DIM);
    return c * rsqrtf(var + 1e-5f) * g + bln;
}

// ==== k_projattn_ln1: attention + full proj row + residual + LN1 -> h1 ======
__global__ void __launch_bounds__(256) k_projattn_ln1(const float* __restrict__ qkvw,
                        const float* __restrict__ ow, const float* __restrict__ ob,
                        const float* __restrict__ scalew,
                        const float* __restrict__ ln1_g, const float* __restrict__ ln1_b,
                        float* __restrict__ h1w)
{
    int row = blockIdx.x;                // b*SEQ + i, 80 blocks
    int b = row / SEQ, i = row % SEQ;
    int tid = threadIdx.x;
    int h = tid >> 6, l = tid & 63;
    __shared__ float xs[DIM];
    __shared__ float red[4];
    const float* base = qkvw + (size_t)b*SEQ*3*DIM;
    float qv = base[(size_t)i*3*DIM + h*DHEAD + l];
    float pj[SEQ];
    #pragma unroll
    for (int j=0;j<SEQ;j++){
        float pr = qv * base[(size_t)j*3*DIM + DIM + h*DHEAD + l];
        for (int o=32;o>0;o>>=1) pr += __shfl_xor(pr,o,64);
        pj[j] = pr * 0.125f;
    }
    float m = pj[0];
    #pragma unroll
    for (int j=1;j<SEQ;j++) m = fmaxf(m, pj[j]);
    float ssum = 0.f;
    #pragma unroll
    for (int j=0;j<SEQ;j++){ pj[j] = __expf(pj[j]-m); ssum += pj[j]; }
    float inv = 1.f/ssum;
    float o = 0.f;
    #pragma unroll
    for (int j=0;j<SEQ;j++) o += pj[j]*inv * base[(size_t)j*3*DIM + 2*DIM + h*DHEAD + l];
    xs[tid] = o;
    __syncthreads();
    // proj col = tid over K=256
    float acc = 0.f;
    #pragma unroll 8
    for (int dp=0; dp<DIM; ++dp) acc += xs[dp] * ow[(size_t)dp*DIM + tid];
    float v = acc + ob[tid] + scalew[(size_t)row*DIM + tid];
    float h1 = block_ln(v, tid, red, ln1_g[tid], ln1_b[tid]);
    h1w[(size_t)row*DIM + tid] = h1;
}

// ==== k_mlp_gab: mlp1+gelu + mlp2 + residual + LN2 + gab (per row) ==========
__global__ void __launch_bounds__(256) k_mlp_gab(const float* __restrict__ h1w,
                        const float* __restrict__ w1, const float* __restrict__ b1,
                        const float* __restrict__ w2, const float* __restrict__ b2v,
                        const float* __restrict__ ln2_g, const float* __restrict__ ln2_b,
                        const float* __restrict__ gw1, const float* __restrict__ gb1,
                        float* __restrict__ sew, float* __restrict__ gaw, float* __restrict__ gbw)
{
    int row = blockIdx.x;                // 80 blocks
    int tid = threadIdx.x;
    __shared__ float xs[DIM];
    __shared__ float hid[4*DIM];
    __shared__ float red[4];
    float h1 = h1w[(size_t)row*DIM + tid];
    xs[tid] = h1;
    __syncthreads();
    // mlp1: 4 cols per thread
    #pragma unroll
    for (int c=0;c<4;c++){
        int col = c*256 + tid;
        float acc = 0.f;
        #pragma unroll 8
        for (int dp=0; dp<DIM; ++dp) acc += xs[dp] * w1[(size_t)dp*1024 + col];
        acc += b1[col];
        hid[col] = 0.5f*acc*(1.f + erff(acc*0.70710678118654752f));
    }
    __syncthreads();
    // mlp2: col = tid over K=1024
    float acc2 = 0.f;
    #pragma unroll 8
    for (int dp=0; dp<1024; ++dp) acc2 += hid[dp] * w2[(size_t)dp*DIM + tid];
    float v = acc2 + b2v[tid] + h1;
    float se = block_ln(v, tid, red, ln2_g[tid], ln2_b[tid]);
    sew[(size_t)row*DIM + tid] = se;
    __syncthreads();
    xs[tid] = se;          // reuse xs (h1 dead)
    __syncthreads();
    // gab: cols tid for both halves
    float aA = 0.f, aB = 0.f;
    #pragma unroll 8
    for (int dp=0; dp<DIM; ++dp){
        float xv = xs[dp];
        aA += xv * gw1[(size_t)dp*DIM + tid];
        aB += xv * gw1[(size_t)(DIM+dp)*DIM + tid];
    }
    gaw[(size_t)row*DIM + tid] = aA + gb1[tid];
    gbw[(size_t)row*DIM + tid] = aB;
}

// ---- gout with fused gadj + gmix + final modulation ------------------------
__global__ void __launch_bounds__(256) k_goutfin(const float* __restrict__ gaw,
                        const float* __restrict__ gbw,
                        const float* __restrict__ gw2, const float* __restrict__ gb2,
                        const float* __restrict__ gbase,
                        const float* __restrict__ sew,
                        const float* __restrict__ ggw, const float* __restrict__ ggb,
                        const float* __restrict__ impw, const float* __restrict__ imp_b,
                        float* __restrict__ out0, float* __restrict__ out_gadj)
{
    int row = blockIdx.x / 4;            // b*SEQ + i
    int n0 = (blockIdx.x % 4) * 64;
    int b = row / SEQ, i = row % SEQ;
    int tid = threadIdx.x;
    int wave = tid >> 6, lane = tid & 63;
    __shared__ float dyn_s[SEQ];
    __shared__ float xs[DIM];
    __shared__ float part[4][64];
    for (int j = wave; j < SEQ; j += 4){
        const float* gar = gaw + (size_t)row*DIM;
        const float* gbr = gbw + ((size_t)b*SEQ + j)*DIM;
        float acc = 0.f;
        #pragma unroll
        for (int m=0;m<4;m++){
            int dd = lane + m*64;
            float v = gar[dd] + gbr[dd];
            float e = (v>0.f) ? v : (__expf(v)-1.f);
            acc += e * gw2[dd];
        }
        for (int o=32;o>0;o>>=1) acc += __shfl_xor(acc,o,64);
        if (lane==0) dyn_s[j] = acc;
    }
    __syncthreads();
    float gc[SEQ];
    {
        float sb2 = gb2[0];
        float m = -1e30f;
        #pragma unroll
        for (int j=0;j<SEQ;j++){
            float sg = 1.f/(1.f+__expf(-(dyn_s[j]+sb2)));
            gc[j] = gbase[i*SEQ+j] + sg;
            m = fmaxf(m, gc[j]);
        }
        float ssum=0.f;
        #pragma unroll
        for (int j=0;j<SEQ;j++){ gc[j]=__expf(gc[j]-m); ssum+=gc[j]; }
        float inv = 1.f/ssum;
        #pragma unroll
        for (int j=0;j<SEQ;j++) gc[j] *= inv;
    }
    if (n0 == 0 && tid < SEQ) out_gadj[((size_t)b*SEQ+i)*SEQ + tid] = gc[tid];
    float t = 0.f;
    #pragma unroll
    for (int j=0;j<SEQ;j++) t += gc[j]*sew[((size_t)b*SEQ + j)*DIM + tid];
    xs[tid] = t;
    __syncthreads();
    int c = tid & 63, s = tid >> 6;
    const float* wp = ggw + (size_t)(s*64)*DIM + n0 + c;
    const float* xp = xs + s*64;
    float acc = 0.f;
    #pragma unroll 8
    for (int k=0;k<64;++k) acc += xp[k] * wp[(size_t)k*DIM];
    part[s][c] = acc;
    __syncthreads();
    if (s == 0){
        float g = ggb[n0+c] + part[0][c]+part[1][c]+part[2][c]+part[3][c];
        size_t o = (size_t)row*DIM + n0 + c;
        out0[o] = g * impw[o] + imp_b[i];
    }
}

extern "C" void kernel_launch(void* const* d_in, const int* in_sizes, int n_in,
                              void* d_out, int out_size, void* d_ws, size_t ws_size,
                              hipStream_t stream)
{
    const float* feature      = (const float*)d_in[0];
    const float* l_adj_w      = (const float*)d_in[1];
    const float* l_sim_w1     = (const float*)d_in[2];
    const float* l_sim_b1     = (const float*)d_in[3];
    const float* l_sim_w2     = (const float*)d_in[4];
    const float* l_sim_b2     = (const float*)d_in[5];
    const float* l_pos_factor = (const float*)d_in[6];
    const float* l_pos_enc    = (const float*)d_in[7];
    const float* l_gcn_w      = (const float*)d_in[8];
    const float* l_gcn_b      = (const float*)d_in[9];
    const float* g_adj_w      = (const float*)d_in[10];
    const float* g_sim_w1     = (const float*)d_in[11];
    const float* g_sim_b1     = (const float*)d_in[12];
    const float* g_sim_w2     = (const float*)d_in[13];
    const float* g_sim_b2     = (const float*)d_in[14];
    const float* g_pos_factor = (const float*)d_in[15];
    const float* g_pos_enc    = (const float*)d_in[16];
    const float* g_gcn_w      = (const float*)d_in[17];
    const float* g_gcn_b      = (const float*)d_in[18];
    const float* qkv_w        = (const float*)d_in[19];
    const float* qkv_b        = (const float*)d_in[20];
    const float* attn_ow      = (const float*)d_in[21];
    const float* attn_ob      = (const float*)d_in[22];
    const float* ln1_g        = (const float*)d_in[23];
    const float* ln1_b        = (const float*)d_in[24];
    const float* ln2_g        = (const float*)d_in[25];
    const float* ln2_b        = (const float*)d_in[26];
    const float* mlp_w1       = (const float*)d_in[27];
    const float* mlp_b1       = (const float*)d_in[28];
    const float* mlp_w2       = (const float*)d_in[29];
    const float* mlp_b2       = (const float*)d_in[30];
    const float* imp_w        = (const float*)d_in[31];
    const float* imp_b        = (const float*)d_in[32];

    float* out0      = (float*)d_out;
    float* out_gadj  = out0 + (size_t)BATCH*NBANDS*DIM;
    float* out_local = out_gadj + (size_t)BATCH*NBANDS*NBANDS;

    const size_t BIG = (size_t)NBANDS*BATCH*NNODE*DIM;           // 1,310,720 elems
    ushort_t* xtb   = (ushort_t*)d_ws;
    ushort_t* aab   = xtb + BIG;
    ushort_t* bbb   = aab + BIG;
    ushort_t* xtT   = bbb + BIG;
    ushort_t* yb    = aab;                                       // aab dead after dyn
    ushort_t* w1bt  = xtT + BIG;
    ushort_t* gwbt  = w1bt + (size_t)NBANDS*512*DIM;
    ushort_t* combb = gwbt + (size_t)NBANDS*DIM*DIM;
    float* fp = (float*)(combb + (size_t)NBANDS*BATCH*NNODE*NNODE);
    float* sbase  = fp; fp += NBANDS*NNODE*NNODE;
    float* gbase  = fp; fp += 32;
    float* scalew = fp; fp += BATCH*SEQ*DIM;
    float* impw   = fp; fp += BATCH*SEQ*DIM;
    float* qkvw   = fp; fp += BATCH*SEQ*3*DIM;
    float* h1w    = fp; fp += BATCH*SEQ*DIM;
    float* sew    = fp; fp += BATCH*SEQ*DIM;
    float* gaw    = fp; fp += BATCH*SEQ*DIM;
    float* gbw    = fp; fp += BATCH*SEQ*DIM;

    k_head<<<641, 256, 0, stream>>>(l_adj_w, l_pos_enc, l_pos_factor,
                                    g_adj_w, g_pos_enc, g_pos_factor,
                                    sbase, gbase,
                                    l_sim_w1, l_gcn_w, w1bt, gwbt,
                                    feature, xtb, xtT);
    k_ab_mfma<<<NBANDS*BATCH*8, 256, 0, stream>>>(xtb, w1bt, l_sim_b1, aab, bbb);
    k_dyn_comb<<<NBANDS*BATCH*16, 256, 0, stream>>>(aab, bbb, l_sim_w2, l_sim_b2, sbase, combb);
    k_y_mfma<<<NBANDS*BATCH*4, 256, 0, stream>>>(combb, xtT, yb);
    k_gcn_qkv<<<NBANDS*BATCH, 256, 0, stream>>>(yb, gwbt, l_gcn_b, imp_w, qkv_w, qkv_b,
                                                out_local, scalew, impw, qkvw);
    k_projattn_ln1<<<BATCH*SEQ, 256, 0, stream>>>(qkvw, attn_ow, attn_ob, scalew,
                                                  ln1_g, ln1_b, h1w);
    k_mlp_gab<<<BATCH*SEQ, 256, 0, stream>>>(h1w, mlp_w1, mlp_b1, mlp_w2, mlp_b2,
                                             ln2_g, ln2_b, g_sim_w1, g_sim_b1,
                                             sew, gaw, gbw);
    k_goutfin<<<BATCH*SEQ*4, 256, 0, stream>>>(gaw, gbw, g_sim_w2, g_sim_b2, gbase,
                                               sew, g_gcn_w, g_gcn_b, impw, imp_b,
                                               out0, out_gadj);
}

// Round 12
// 217.269 us; speedup vs baseline: 2.7254x; 1.4780x over previous
//
#include <hip/hip_runtime.h>
#include <hip/hip_bf16.h>

#define NBANDS 5
#define BATCH  16
#define DIM    256
#define NNODE  64
#define SEQ    5
#define NHEAD  4
#define DHEAD  64

typedef __hip_bfloat16 bf16;
typedef unsigned short ushort_t;
typedef __attribute__((ext_vector_type(8))) short short8;   // 8 bf16 (4 VGPRs)
typedef __attribute__((ext_vector_type(4))) float float4v;  // 4 fp32 acc

__device__ __forceinline__ float bu2f(ushort_t u){
    bf16 h = *reinterpret_cast<bf16*>(&u);
    return __bfloat162float(h);
}
__device__ __forceinline__ ushort_t f2bu(float x){
    bf16 h = __float2bfloat16(x);
    return *reinterpret_cast<ushort_t*>(&h);
}

// ============ k_head: bases + MFMA weight prep + feature transpose ============
// blocks [0,80):   local sbase, 4 rows/block
// block  80:       global gbase
// blocks [81,321): w1/gw transpose+convert (15 insts x 16 tiles)
// blocks [321,641): feature -> xtb + xtT, one (k,b,dt) quarter per block
__global__ void __launch_bounds__(256) k_head(
    const float* __restrict__ l_adj_w, const float* __restrict__ l_pos_enc,
    const float* __restrict__ l_pf,
    const float* __restrict__ g_adj_w, const float* __restrict__ g_pos_enc,
    const float* __restrict__ g_pf,
    float* __restrict__ sbase, float* __restrict__ gbase,
    const float* __restrict__ w1, const float* __restrict__ gw,
    ushort_t* __restrict__ w1bt, ushort_t* __restrict__ gwbt,
    const float* __restrict__ feat,
    ushort_t* __restrict__ xtb, ushort_t* __restrict__ xtT)
{
    int blk = blockIdx.x;
    int tid = threadIdx.x;
    __shared__ ushort_t tile[64][65];

    if (blk < 80) {
        int r = blk*4 + (tid>>6);
        int k = r >> 6, i = r & 63;
        int t = tid & 63;
        float aw = l_adj_w[(k*NNODE + i)*NNODE + t];
        float pe = l_pos_enc[(k*NNODE + i)*NNODE + t];
        float m1 = aw, m2 = pe;
        for (int o=32;o>0;o>>=1){ m1 = fmaxf(m1, __shfl_xor(m1,o,64)); m2 = fmaxf(m2, __shfl_xor(m2,o,64)); }
        float e1 = __expf(aw-m1), e2 = __expf(pe-m2);
        float s1=e1, s2=e2;
        for (int o=32;o>0;o>>=1){ s1 += __shfl_xor(s1,o,64); s2 += __shfl_xor(s2,o,64); }
        float pf = l_pf[k];
        sbase[(k*NNODE+i)*NNODE + t] = e1/s1 + pf*(e2/s2);
    } else if (blk == 80) {
        if (tid < NBANDS) {
            int i = tid;
            float r1[NBANDS], r2[NBANDS];
            float m1=-1e30f, m2=-1e30f;
            for (int j=0;j<NBANDS;j++){
                r1[j]=g_adj_w[i*NBANDS+j]; r2[j]=g_pos_enc[i*NBANDS+j];
                m1=fmaxf(m1,r1[j]); m2=fmaxf(m2,r2[j]);
            }
            float s1=0.f,s2=0.f;
            for (int j=0;j<NBANDS;j++){ r1[j]=__expf(r1[j]-m1); r2[j]=__expf(r2[j]-m2); s1+=r1[j]; s2+=r2[j]; }
            float pf = g_pf[0];
            for (int j=0;j<NBANDS;j++) gbase[i*NBANDS+j] = r1[j]/s1 + pf*(r2[j]/s2);
        }
    } else if (blk < 321) {
        int idx = blk - 81;
        int inst = idx >> 4;
        int t = idx & 15;
        int r0 = (t>>2)*64, c0 = (t&3)*64;
        const float* src; ushort_t* dst;
        if (inst < 10){
            int k = inst>>1, half = inst&1;
            src = w1  + ((size_t)k*512 + half*256)*256;
            dst = w1bt+ ((size_t)k*512 + half*256)*256;
        } else {
            int k = inst-10;
            src = gw  + (size_t)k*65536;
            dst = gwbt+ (size_t)k*65536;
        }
        int jj = tid & 63, i4 = tid >> 6;
        for (int p=0;p<16;p++){
            int i = p*4 + i4;
            tile[i][jj] = f2bu(src[(size_t)(r0+i)*256 + c0 + jj]);
        }
        __syncthreads();
        for (int p=0;p<16;p++){
            int i = p*4 + i4;
            dst[(size_t)(c0+i)*256 + r0 + jj] = tile[jj][i];
        }
    } else {
        int idx = blk - 321;                   // (k,b,dt)
        int k = idx >> 6;
        int b = (idx >> 2) & 15;
        int dt = idx & 3;
        const float* src = feat + ((size_t)b*NBANDS*DIM + (size_t)k*DIM)*NNODE; // [D][N]
        ushort_t* dst = xtb + (size_t)(k*BATCH+b)*NNODE*DIM;                    // [N][D]
        ushort_t* dstT = xtT + (size_t)(k*BATCH+b)*DIM*NNODE;                   // [D][N]
        for (int u=0; u<16; ++u){
            int i = dt*4096 + u*256 + tid;
            dstT[i] = f2bu(src[i]);
        }
        for (int r=0;r<16;r++){
            int dp = r*4 + (tid>>6);
            int n  = tid & 63;
            tile[dp][n] = f2bu(src[(size_t)(dt*64+dp)*NNODE + n]);
        }
        __syncthreads();
        for (int r=0;r<16;r++){
            int n  = r*4 + (tid>>6);
            int dp = tid & 63;
            dst[(size_t)n*DIM + dt*64 + dp] = tile[dp][n];
        }
    }
}

// ---- MFMA a/bp: per band GEMM [1024 x 256] @ [256 x 512] -> aab|bbb bf16 ----
__global__ void __launch_bounds__(256) k_ab_mfma(const ushort_t* __restrict__ xtb,
                        const ushort_t* __restrict__ w1bt, const float* __restrict__ b1,
                        ushort_t* __restrict__ aab, ushort_t* __restrict__ bbb)
{
    int blk = blockIdx.x;                 // 5*16*8
    int kband = blk / (BATCH*8);
    int b = (blk/8) % BATCH;
    int nblk = blk & 7;
    int tid = threadIdx.x;
    int wave = tid>>6, lane = tid&63;
    int c16 = lane & 15, quad = lane >> 4;
    int m0 = wave*16;
    size_t rowbase = (size_t)(kband*BATCH+b)*NNODE;
    const ushort_t* Aptr = xtb + (rowbase + m0 + c16)*DIM + quad*8;
    const ushort_t* Bbase = w1bt + (size_t)kband*512*DIM;
    int ncol0 = nblk*64;
    const ushort_t* Bptr0 = Bbase + (size_t)(ncol0 +  0 + c16)*DIM + quad*8;
    const ushort_t* Bptr1 = Bbase + (size_t)(ncol0 + 16 + c16)*DIM + quad*8;
    const ushort_t* Bptr2 = Bbase + (size_t)(ncol0 + 32 + c16)*DIM + quad*8;
    const ushort_t* Bptr3 = Bbase + (size_t)(ncol0 + 48 + c16)*DIM + quad*8;
    float4v acc0 = {0.f,0.f,0.f,0.f}, acc1 = acc0, acc2 = acc0, acc3 = acc0;
    #pragma unroll
    for (int ks=0; ks<8; ++ks){
        short8 a  = *reinterpret_cast<const short8*>(Aptr  + ks*32);
        short8 b0 = *reinterpret_cast<const short8*>(Bptr0 + ks*32);
        short8 b1v= *reinterpret_cast<const short8*>(Bptr1 + ks*32);
        short8 b2 = *reinterpret_cast<const short8*>(Bptr2 + ks*32);
        short8 b3 = *reinterpret_cast<const short8*>(Bptr3 + ks*32);
        acc0 = __builtin_amdgcn_mfma_f32_16x16x32_bf16(a, b0, acc0, 0,0,0);
        acc1 = __builtin_amdgcn_mfma_f32_16x16x32_bf16(a, b1v, acc1, 0,0,0);
        acc2 = __builtin_amdgcn_mfma_f32_16x16x32_bf16(a, b2, acc2, 0,0,0);
        acc3 = __builtin_amdgcn_mfma_f32_16x16x32_bf16(a, b3, acc3, 0,0,0);
    }
    int half = nblk >> 2;
    int cbase = (nblk & 3)*64;
    ushort_t* dst = half ? bbb : aab;
    float4v accs[4] = {acc0, acc1, acc2, acc3};
    #pragma unroll
    for (int nt=0; nt<4; ++nt){
        int cg = cbase + nt*16 + c16;
        float bias = half ? 0.f : b1[kband*DIM + cg];
        #pragma unroll
        for (int r=0;r<4;r++){
            int m = m0 + quad*4 + r;
            dst[(rowbase + m)*DIM + cg] = f2bu(accs[nt][r] + bias);
        }
    }
}

// ------- dyn+comb: lane j owns pair (i,j); b-tile staged in LDS -------------
__global__ void __launch_bounds__(256) k_dyn_comb(const ushort_t* __restrict__ aab,
                           const ushort_t* __restrict__ bbb,
                           const float* __restrict__ w2, const float* __restrict__ b2arr,
                           const float* __restrict__ sbase,
                           ushort_t* __restrict__ combb)
{
    int blk = blockIdx.x;                     // 5*16*16 blocks, 4 i-rows each
    int k = blk / (BATCH*16);
    int b = (blk / 16) % BATCH;
    int i0 = (blk % 16) * 4;
    int kb = k*BATCH + b;
    __shared__ ushort_t bs[64][260];          // [j][d], pad keeps 8B row align
    __shared__ float arows[4][DIM];
    __shared__ float w2s[DIM];
    int tid = threadIdx.x;
    int wave = tid >> 6, lane = tid & 63;
    const ushort_t* bsrc = bbb + (size_t)kb*NNODE*DIM;
    for (int u=0; u<16; ++u){
        int idx = u*1024 + tid*4;
        int row = idx >> 8, col = idx & 255;
        *reinterpret_cast<ushort4*>(&bs[row][col]) =
            *reinterpret_cast<const ushort4*>(&bsrc[(size_t)row*DIM + col]);
    }
    for (int r=0;r<4;r++) arows[r][tid] = bu2f(aab[((size_t)kb*NNODE + i0 + r)*DIM + tid]);
    w2s[tid] = w2[k*DIM + tid];
    __syncthreads();

    int i = i0 + wave;
    float acc = 0.f;
    #pragma unroll 4
    for (int dd=0; dd<64; ++dd){
        ushort4 bv = *reinterpret_cast<const ushort4*>(&bs[lane][dd*4]);
        float4 av = *reinterpret_cast<const float4*>(&arows[wave][dd*4]);
        float4 wv = *reinterpret_cast<const float4*>(&w2s[dd*4]);
        float v0 = av.x + bu2f(bv.x);
        float v1 = av.y + bu2f(bv.y);
        float v2 = av.z + bu2f(bv.z);
        float v3 = av.w + bu2f(bv.w);
        float e0 = (v0>0.f)? v0 : (__expf(v0)-1.f);
        float e1 = (v1>0.f)? v1 : (__expf(v1)-1.f);
        float e2 = (v2>0.f)? v2 : (__expf(v2)-1.f);
        float e3 = (v3>0.f)? v3 : (__expf(v3)-1.f);
        acc += e0*wv.x + e1*wv.y + e2*wv.z + e3*wv.w;
    }
    float sb2 = b2arr[k];
    float sg = 1.f/(1.f + __expf(-(acc + sb2)));
    float val = sbase[(k*NNODE + i)*NNODE + lane] + sg;
    float m = val;
    for (int o=32;o>0;o>>=1) m = fmaxf(m, __shfl_xor(m,o,64));
    float e = __expf(val - m);
    float s = e;
    for (int o=32;o>0;o>>=1) s += __shfl_xor(s,o,64);
    combb[((size_t)kb*NNODE + i)*NNODE + lane] = f2bu(e/s);
}

// ---- MFMA y: per (k,b) GEMM [64 x 64] @ [64 x 256] -> yb bf16 [kb][n][d] ----
__global__ void __launch_bounds__(256) k_y_mfma(const ushort_t* __restrict__ combb,
                       const ushort_t* __restrict__ xtT,
                       ushort_t* __restrict__ yb)
{
    int blk = blockIdx.x;                 // 5*16*4
    int kband = blk / (BATCH*4);
    int b = (blk/4) % BATCH;
    int nblk = blk & 3;
    int tid = threadIdx.x;
    int wave = tid>>6, lane = tid&63;
    int c16 = lane & 15, quad = lane >> 4;
    int m0 = wave*16;
    int kb = kband*BATCH + b;
    const ushort_t* Aptr = combb + ((size_t)kb*NNODE + m0 + c16)*NNODE + quad*8;  // [n][j]
    const ushort_t* Bbase = xtT + (size_t)kb*DIM*NNODE;                            // [d][j]
    int ncol0 = nblk*64;
    const ushort_t* Bptr0 = Bbase + (size_t)(ncol0 +  0 + c16)*NNODE + quad*8;
    const ushort_t* Bptr1 = Bbase + (size_t)(ncol0 + 16 + c16)*NNODE + quad*8;
    const ushort_t* Bptr2 = Bbase + (size_t)(ncol0 + 32 + c16)*NNODE + quad*8;
    const ushort_t* Bptr3 = Bbase + (size_t)(ncol0 + 48 + c16)*NNODE + quad*8;
    float4v acc0 = {0.f,0.f,0.f,0.f}, acc1 = acc0, acc2 = acc0, acc3 = acc0;
    #pragma unroll
    for (int ks=0; ks<2; ++ks){
        short8 a  = *reinterpret_cast<const short8*>(Aptr  + ks*32);
        short8 b0 = *reinterpret_cast<const short8*>(Bptr0 + ks*32);
        short8 b1v= *reinterpret_cast<const short8*>(Bptr1 + ks*32);
        short8 b2 = *reinterpret_cast<const short8*>(Bptr2 + ks*32);
        short8 b3 = *reinterpret_cast<const short8*>(Bptr3 + ks*32);
        acc0 = __builtin_amdgcn_mfma_f32_16x16x32_bf16(a, b0, acc0, 0,0,0);
        acc1 = __builtin_amdgcn_mfma_f32_16x16x32_bf16(a, b1v, acc1, 0,0,0);
        acc2 = __builtin_amdgcn_mfma_f32_16x16x32_bf16(a, b2, acc2, 0,0,0);
        acc3 = __builtin_amdgcn_mfma_f32_16x16x32_bf16(a, b3, acc3, 0,0,0);
    }
    size_t rowbase = (size_t)kb*NNODE;
    float4v accs[4] = {acc0, acc1, acc2, acc3};
    #pragma unroll
    for (int nt=0; nt<4; ++nt){
        int cg = ncol0 + nt*16 + c16;
        #pragma unroll
        for (int r=0;r<4;r++){
            int m = m0 + quad*4 + r;
            yb[(rowbase + m)*DIM + cg] = f2bu(accs[nt][r]);
        }
    }
}

// ---- MFMA gcn + fused scale/importance: [64x256]@[256x256]+bias ----
__global__ void __launch_bounds__(256) k_gcn_mfma(const ushort_t* __restrict__ yb,
                         const ushort_t* __restrict__ gwbt, const float* __restrict__ gb,
                         const float* __restrict__ imp_w,
                         float* __restrict__ out_local,
                         float* __restrict__ scalew, float* __restrict__ impw)
{
    int blk = blockIdx.x;                 // 5*16*4
    int kband = blk / (BATCH*4);
    int b = (blk/4) % BATCH;
    int nblk = blk & 3;
    int tid = threadIdx.x;
    int wave = tid>>6, lane = tid&63;
    int c16 = lane & 15, quad = lane >> 4;
    int m0 = wave*16;
    int kb = kband*BATCH + b;
    __shared__ float iw_s[NNODE];
    __shared__ float sred[4][64];
    __shared__ float ired[4][64];
    if (tid < NNODE) iw_s[tid] = imp_w[kband*NNODE + tid];
    const ushort_t* Aptr = yb + ((size_t)kb*NNODE + m0 + c16)*DIM + quad*8;  // [n][d]
    const ushort_t* Bbase = gwbt + (size_t)kband*DIM*DIM;                    // [col][kk]
    int ncol0 = nblk*64;
    const ushort_t* Bptr0 = Bbase + (size_t)(ncol0 +  0 + c16)*DIM + quad*8;
    const ushort_t* Bptr1 = Bbase + (size_t)(ncol0 + 16 + c16)*DIM + quad*8;
    const ushort_t* Bptr2 = Bbase + (size_t)(ncol0 + 32 + c16)*DIM + quad*8;
    const ushort_t* Bptr3 = Bbase + (size_t)(ncol0 + 48 + c16)*DIM + quad*8;
    float4v acc0 = {0.f,0.f,0.f,0.f}, acc1 = acc0, acc2 = acc0, acc3 = acc0;
    #pragma unroll
    for (int ks=0; ks<8; ++ks){
        short8 a  = *reinterpret_cast<const short8*>(Aptr  + ks*32);
        short8 b0 = *reinterpret_cast<const short8*>(Bptr0 + ks*32);
        short8 b1v= *reinterpret_cast<const short8*>(Bptr1 + ks*32);
        short8 b2 = *reinterpret_cast<const short8*>(Bptr2 + ks*32);
        short8 b3 = *reinterpret_cast<const short8*>(Bptr3 + ks*32);
        acc0 = __builtin_amdgcn_mfma_f32_16x16x32_bf16(a, b0, acc0, 0,0,0);
        acc1 = __builtin_amdgcn_mfma_f32_16x16x32_bf16(a, b1v, acc1, 0,0,0);
        acc2 = __builtin_amdgcn_mfma_f32_16x16x32_bf16(a, b2, acc2, 0,0,0);
        acc3 = __builtin_amdgcn_mfma_f32_16x16x32_bf16(a, b3, acc3, 0,0,0);
    }
    __syncthreads();   // iw_s visible
    float4v accs[4] = {acc0, acc1, acc2, acc3};
    #pragma unroll
    for (int nt=0; nt<4; ++nt){
        int cg = ncol0 + nt*16 + c16;
        float bias = gb[kband*DIM + cg];
        float v0 = accs[nt][0]+bias, v1 = accs[nt][1]+bias, v2 = accs[nt][2]+bias, v3 = accs[nt][3]+bias;
        float4 v = make_float4(v0, v1, v2, v3);
        float* dst = out_local + ((size_t)(b*NBANDS + kband)*DIM + cg)*NNODE + m0 + quad*4;
        *reinterpret_cast<float4*>(dst) = v;
        int nb = m0 + quad*4;
        float s  = v0 + v1 + v2 + v3;
        float di = v0*iw_s[nb] + v1*iw_s[nb+1] + v2*iw_s[nb+2] + v3*iw_s[nb+3];
        s  += __shfl_xor(s, 16, 64);  s  += __shfl_xor(s, 32, 64);
        di += __shfl_xor(di, 16, 64); di += __shfl_xor(di, 32, 64);
        if (quad == 0){
            sred[wave][nt*16 + c16] = s;
            ired[wave][nt*16 + c16] = di;
        }
    }
    __syncthreads();
    if (tid < 64){
        float s  = sred[0][tid] + sred[1][tid] + sred[2][tid] + sred[3][tid];
        float di = ired[0][tid] + ired[1][tid] + ired[2][tid] + ired[3][tid];
        size_t o = ((size_t)b*SEQ + kband)*DIM + ncol0 + tid;
        scalew[o] = s * (1.f/64.f);
        impw[o]   = di;
    }
}

// ---- generic sliced GEMV: out[row][n] = act(bias[n] + sum_k x[row][k] w[k][n]) ----
template<int COLS, int SLICES>
__global__ void __launch_bounds__(256) k_gemv(const float* __restrict__ x, const float* __restrict__ w,
                       const float* __restrict__ bias, float* __restrict__ out,
                       int K, int N, int act)
{
    int chunks = N / COLS;
    int row = blockIdx.x / chunks;
    int n0 = (blockIdx.x % chunks) * COLS;
    int c = threadIdx.x % COLS, s = threadIdx.x / COLS;
    __shared__ float xs[1024];
    __shared__ float part[SLICES][COLS];
    for (int i = threadIdx.x; i < K; i += 256) xs[i] = x[(size_t)row*K + i];
    __syncthreads();
    int klen = K / SLICES;
    const float* wp = w + (size_t)(s*klen)*N + n0 + c;
    const float* xp = xs + s*klen;
    float acc = 0.f;
    #pragma unroll 8
    for (int i = 0; i < klen; ++i) acc += xp[i] * wp[(size_t)i*N];
    part[s][c] = acc;
    __syncthreads();
    if (s == 0){
        float v = bias[n0+c];
        #pragma unroll
        for (int q=0;q<SLICES;q++) v += part[q][c];
        if (act) v = 0.5f*v*(1.f + erff(v*0.70710678118654752f));
        out[(size_t)row*N + n0 + c] = v;
    }
}

// ---- proj with fused per-row attention prologue ----------------------------
__global__ void __launch_bounds__(256) k_projattn(const float* __restrict__ qkvw,
                        const float* __restrict__ ow, const float* __restrict__ ob,
                        float* __restrict__ projw)
{
    int row = blockIdx.x / 4;            // b*SEQ + i
    int n0 = (blockIdx.x % 4) * 64;
    int b = row / SEQ, i = row % SEQ;
    int tid = threadIdx.x;
    int h = tid >> 6, l = tid & 63;
    __shared__ float xs[DIM];
    __shared__ float part[4][64];
    const float* base = qkvw + (size_t)b*SEQ*3*DIM;
    // attention row i, head h (butterfly leaves sum in all lanes)
    float qv = base[(size_t)i*3*DIM + h*DHEAD + l];
    float pj[SEQ];
    #pragma unroll
    for (int j=0;j<SEQ;j++){
        float p = qv * base[(size_t)j*3*DIM + DIM + h*DHEAD + l];
        for (int o=32;o>0;o>>=1) p += __shfl_xor(p,o,64);
        pj[j] = p * 0.125f;
    }
    float m = pj[0];
    #pragma unroll
    for (int j=1;j<SEQ;j++) m = fmaxf(m, pj[j]);
    float ssum = 0.f;
    #pragma unroll
    for (int j=0;j<SEQ;j++){ pj[j] = __expf(pj[j]-m); ssum += pj[j]; }
    float inv = 1.f/ssum;
    float o = 0.f;
    #pragma unroll
    for (int j=0;j<SEQ;j++) o += pj[j]*inv * base[(size_t)j*3*DIM + 2*DIM + h*DHEAD + l];
    xs[tid] = o;
    __syncthreads();
    // proj chunk gemv
    int c = tid & 63, s = tid >> 6;
    const float* wp = ow + (size_t)(s*64)*DIM + n0 + c;
    const float* xp = xs + s*64;
    float acc = 0.f;
    #pragma unroll 8
    for (int k=0;k<64;++k) acc += xp[k] * wp[(size_t)k*DIM];
    part[s][c] = acc;
    __syncthreads();
    if (s == 0){
        projw[(size_t)row*DIM + n0 + c] = ob[n0+c] + part[0][c]+part[1][c]+part[2][c]+part[3][c];
    }
}

// ---------------- block LayerNorm over 256 elems ----------------------------
__device__ __forceinline__ float block_ln(float v, int tid, float* red, float g, float bln)
{
    float s = v;
    for (int o=32;o>0;o>>=1) s += __shfl_xor(s,o,64);
    int wave = tid>>6, lane = tid&63;
    if (lane==0) red[wave] = s;
    __syncthreads();
    float mean = (red[0]+red[1]+red[2]+red[3]) * (1.f/DIM);
    float c = v - mean;
    float q = c*c;
    for (int o=32;o>0;o>>=1) q += __shfl_xor(q,o,64);
    __syncthreads();
    if (lane==0) red[wave] = q;
    __syncthreads();
    float var = (red[0]+red[1]+red[2]+red[3]) * (1.f/DIM);
    return c * rsqrtf(var + 1e-5f) * g + bln;
}

// ---- mlp1 with fused LN1 prologue ------------------------------------------
__global__ void __launch_bounds__(256) k_mlp1_ln(const float* __restrict__ projw,
                         const float* __restrict__ scalew,
                         const float* __restrict__ ln1_g, const float* __restrict__ ln1_b,
                         const float* __restrict__ w1, const float* __restrict__ b1,
                         float* __restrict__ h1w, float* __restrict__ mhw)
{
    int row = blockIdx.x / 16;
    int n0 = (blockIdx.x % 16) * 64;
    int tid = threadIdx.x;
    __shared__ float xs[DIM];
    __shared__ float red[4];
    __shared__ float part[4][64];
    float v = projw[(size_t)row*DIM + tid] + scalew[(size_t)row*DIM + tid];
    float h = block_ln(v, tid, red, ln1_g[tid], ln1_b[tid]);
    xs[tid] = h;
    if ((blockIdx.x % 16) == 0) h1w[(size_t)row*DIM + tid] = h;
    __syncthreads();
    int c = tid & 63, s = tid >> 6;
    const float* wp = w1 + (size_t)(s*64)*1024 + n0 + c;
    const float* xp = xs + s*64;
    float acc = 0.f;
    #pragma unroll 8
    for (int i=0;i<64;++i) acc += xp[i] * wp[(size_t)i*1024];
    part[s][c] = acc;
    __syncthreads();
    if (s == 0){
        float o = b1[n0+c] + part[0][c] + part[1][c] + part[2][c] + part[3][c];
        o = 0.5f*o*(1.f + erff(o*0.70710678118654752f));
        mhw[(size_t)row*1024 + n0 + c] = o;
    }
}

// ---- gab with fused LN2 prologue -------------------------------------------
__global__ void __launch_bounds__(256) k_gab_ln(const float* __restrict__ m2w,
                        const float* __restrict__ h1w,
                        const float* __restrict__ ln2_g, const float* __restrict__ ln2_b,
                        const float* __restrict__ gw1, const float* __restrict__ gb1,
                        float* __restrict__ sew, float* __restrict__ gaw, float* __restrict__ gbw)
{
    int row = blockIdx.x / 4;
    int n0 = (blockIdx.x % 4) * 64;
    int tid = threadIdx.x;
    __shared__ float xs[DIM];
    __shared__ float red[4];
    __shared__ float partA[4][64];
    __shared__ float partB[4][64];
    float v = m2w[(size_t)row*DIM + tid] + h1w[(size_t)row*DIM + tid];
    float h = block_ln(v, tid, red, ln2_g[tid], ln2_b[tid]);
    xs[tid] = h;
    if ((blockIdx.x % 4) == 0) sew[(size_t)row*DIM + tid] = h;
    __syncthreads();
    int c = tid & 63, s = tid >> 6;
    const float* wpA = gw1 + (size_t)(s*64)*DIM + n0 + c;
    const float* wpB = wpA + (size_t)DIM*DIM;
    const float* xp = xs + s*64;
    float aA = 0.f, aB = 0.f;
    #pragma unroll 8
    for (int i=0;i<64;++i){
        float xv = xp[i];
        aA += xv * wpA[(size_t)i*DIM];
        aB += xv * wpB[(size_t)i*DIM];
    }
    partA[s][c] = aA;
    partB[s][c] = aB;
    __syncthreads();
    if (s == 0){
        gaw[(size_t)row*DIM + n0 + c] = gb1[n0+c] + partA[0][c]+partA[1][c]+partA[2][c]+partA[3][c];
        gbw[(size_t)row*DIM + n0 + c] = partB[0][c]+partB[1][c]+partB[2][c]+partB[3][c];
    }
}

// ---- gout with fused gadj + gmix + final modulation ------------------------
__global__ void __launch_bounds__(256) k_goutfin(const float* __restrict__ gaw,
                        const float* __restrict__ gbw,
                        const float* __restrict__ gw2, const float* __restrict__ gb2,
                        const float* __restrict__ gbase,
                        const float* __restrict__ sew,
                        const float* __restrict__ ggw, const float* __restrict__ ggb,
                        const float* __restrict__ impw, const float* __restrict__ imp_b,
                        float* __restrict__ out0, float* __restrict__ out_gadj)
{
    int row = blockIdx.x / 4;            // b*SEQ + i
    int n0 = (blockIdx.x % 4) * 64;
    int b = row / SEQ, i = row % SEQ;
    int tid = threadIdx.x;
    int wave = tid >> 6, lane = tid & 63;
    __shared__ float dyn_s[SEQ];
    __shared__ float xs[DIM];
    __shared__ float part[4][64];
    // dyn row i: wave j handles column j (wave 0 also j=4)
    for (int j = wave; j < SEQ; j += 4){
        const float* gar = gaw + (size_t)row*DIM;
        const float* gbr = gbw + ((size_t)b*SEQ + j)*DIM;
        float acc = 0.f;
        #pragma unroll
        for (int m=0;m<4;m++){
            int dd = lane + m*64;
            float v = gar[dd] + gbr[dd];
            float e = (v>0.f) ? v : (__expf(v)-1.f);
            acc += e * gw2[dd];
        }
        for (int o=32;o>0;o>>=1) acc += __shfl_xor(acc,o,64);
        if (lane==0) dyn_s[j] = acc;
    }
    __syncthreads();
    // softmax row (redundant in all threads)
    float gc[SEQ];
    {
        float sb2 = gb2[0];
        float m = -1e30f;
        #pragma unroll
        for (int j=0;j<SEQ;j++){
            float sg = 1.f/(1.f+__expf(-(dyn_s[j]+sb2)));
            gc[j] = gbase[i*SEQ+j] + sg;
            m = fmaxf(m, gc[j]);
        }
        float ssum=0.f;
        #pragma unroll
        for (int j=0;j<SEQ;j++){ gc[j]=__expf(gc[j]-m); ssum+=gc[j]; }
        float inv = 1.f/ssum;
        #pragma unroll
        for (int j=0;j<SEQ;j++) gc[j] *= inv;
    }
    if (n0 == 0 && tid < SEQ) out_gadj[((size_t)b*SEQ+i)*SEQ + tid] = gc[tid];
    // gmix
    float t = 0.f;
    #pragma unroll
    for (int j=0;j<SEQ;j++) t += gc[j]*sew[((size_t)b*SEQ + j)*DIM + tid];
    xs[tid] = t;
    __syncthreads();
    // gout chunk gemv + final modulation
    int c = tid & 63, s = tid >> 6;
    const float* wp = ggw + (size_t)(s*64)*DIM + n0 + c;
    const float* xp = xs + s*64;
    float acc = 0.f;
    #pragma unroll 8
    for (int k=0;k<64;++k) acc += xp[k] * wp[(size_t)k*DIM];
    part[s][c] = acc;
    __syncthreads();
    if (s == 0){
        float g = ggb[n0+c] + part[0][c]+part[1][c]+part[2][c]+part[3][c];
        size_t o = (size_t)row*DIM + n0 + c;
        out0[o] = g * impw[o] + imp_b[i];
    }
}

extern "C" void kernel_launch(void* const* d_in, const int* in_sizes, int n_in,
                              void* d_out, int out_size, void* d_ws, size_t ws_size,
                              hipStream_t stream)
{
    const float* feature      = (const float*)d_in[0];
    const float* l_adj_w      = (const float*)d_in[1];
    const float* l_sim_w1     = (const float*)d_in[2];
    const float* l_sim_b1     = (const float*)d_in[3];
    const float* l_sim_w2     = (const float*)d_in[4];
    const float* l_sim_b2     = (const float*)d_in[5];
    const float* l_pos_factor = (const float*)d_in[6];
    const float* l_pos_enc    = (const float*)d_in[7];
    const float* l_gcn_w      = (const float*)d_in[8];
    const float* l_gcn_b      = (const float*)d_in[9];
    const float* g_adj_w      = (const float*)d_in[10];
    const float* g_sim_w1     = (const float*)d_in[11];
    const float* g_sim_b1     = (const float*)d_in[12];
    const float* g_sim_w2     = (const float*)d_in[13];
    const float* g_sim_b2     = (const float*)d_in[14];
    const float* g_pos_factor = (const float*)d_in[15];
    const float* g_pos_enc    = (const float*)d_in[16];
    const float* g_gcn_w      = (const float*)d_in[17];
    const float* g_gcn_b      = (const float*)d_in[18];
    const float* qkv_w        = (const float*)d_in[19];
    const float* qkv_b        = (const float*)d_in[20];
    const float* attn_ow      = (const float*)d_in[21];
    const float* attn_ob      = (const float*)d_in[22];
    const float* ln1_g        = (const float*)d_in[23];
    const float* ln1_b        = (const float*)d_in[24];
    const float* ln2_g        = (const float*)d_in[25];
    const float* ln2_b        = (const float*)d_in[26];
    const float* mlp_w1       = (const float*)d_in[27];
    const float* mlp_b1       = (const float*)d_in[28];
    const float* mlp_w2       = (const float*)d_in[29];
    const float* mlp_b2       = (const float*)d_in[30];
    const float* imp_w        = (const float*)d_in[31];
    const float* imp_b        = (const float*)d_in[32];

    float* out0      = (float*)d_out;
    float* out_gadj  = out0 + (size_t)BATCH*NBANDS*DIM;
    float* out_local = out_gadj + (size_t)BATCH*NBANDS*NBANDS;

    const size_t BIG = (size_t)NBANDS*BATCH*NNODE*DIM;           // 1,310,720 elems
    ushort_t* xtb   = (ushort_t*)d_ws;
    ushort_t* aab   = xtb + BIG;
    ushort_t* bbb   = aab + BIG;
    ushort_t* xtT   = bbb + BIG;
    ushort_t* yb    = aab;                                       // aab dead after dyn
    ushort_t* w1bt  = xtT + BIG;
    ushort_t* gwbt  = w1bt + (size_t)NBANDS*512*DIM;
    ushort_t* combb = gwbt + (size_t)NBANDS*DIM*DIM;
    float* fp = (float*)(combb + (size_t)NBANDS*BATCH*NNODE*NNODE);
    float* sbase  = fp; fp += NBANDS*NNODE*NNODE;
    float* gbase  = fp; fp += 32;
    float* scalew = fp; fp += BATCH*SEQ*DIM;
    float* impw   = fp; fp += BATCH*SEQ*DIM;
    float* qkvw   = fp; fp += BATCH*SEQ*3*DIM;
    float* projw  = fp; fp += BATCH*SEQ*DIM;
    float* h1w    = fp; fp += BATCH*SEQ*DIM;
    float* mhw    = fp; fp += BATCH*SEQ*4*DIM;
    float* m2w    = fp; fp += BATCH*SEQ*DIM;
    float* sew    = fp; fp += BATCH*SEQ*DIM;
    float* gaw    = fp; fp += BATCH*SEQ*DIM;
    float* gbw    = fp; fp += BATCH*SEQ*DIM;

    const int ROWS = BATCH*SEQ;   // 80

    k_head<<<641, 256, 0, stream>>>(l_adj_w, l_pos_enc, l_pos_factor,
                                    g_adj_w, g_pos_enc, g_pos_factor,
                                    sbase, gbase,
                                    l_sim_w1, l_gcn_w, w1bt, gwbt,
                                    feature, xtb, xtT);
    k_ab_mfma<<<NBANDS*BATCH*8, 256, 0, stream>>>(xtb, w1bt, l_sim_b1, aab, bbb);
    k_dyn_comb<<<NBANDS*BATCH*16, 256, 0, stream>>>(aab, bbb, l_sim_w2, l_sim_b2, sbase, combb);
    k_y_mfma<<<NBANDS*BATCH*4, 256, 0, stream>>>(combb, xtT, yb);
    k_gcn_mfma<<<NBANDS*BATCH*4, 256, 0, stream>>>(yb, gwbt, l_gcn_b, imp_w,
                                                   out_local, scalew, impw);
    k_gemv<64,4><<<ROWS*12, 256, 0, stream>>>(scalew, qkv_w, qkv_b, qkvw, 256, 768, 0);
    k_projattn<<<ROWS*4, 256, 0, stream>>>(qkvw, attn_ow, attn_ob, projw);
    k_mlp1_ln<<<ROWS*16, 256, 0, stream>>>(projw, scalew, ln1_g, ln1_b, mlp_w1, mlp_b1, h1w, mhw);
    k_gemv<32,8><<<ROWS*8, 256, 0, stream>>>(mhw, mlp_w2, mlp_b2, m2w, 1024, 256, 0);
    k_gab_ln<<<ROWS*4, 256, 0, stream>>>(m2w, h1w, ln2_g, ln2_b, g_sim_w1, g_sim_b1, sew, gaw, gbw);
    k_goutfin<<<ROWS*4, 256, 0, stream>>>(gaw, gbw, g_sim_w2, g_sim_b2, gbase,
                                          sew, g_gcn_w, g_gcn_b, impw, imp_b,
                                          out0, out_gadj);
}